// Round 1
// baseline (253.343 us; speedup 1.0000x reference)
//
#include <hip/hip_runtime.h>
#include <hip/hip_bf16.h>

#define BB 4
#define SS 2048
#define DD 768
#define HH 12
#define TD 2304  // 3*D

typedef __bf16 bf16_t;
typedef bf16_t bf16x8 __attribute__((ext_vector_type(8)));
typedef float f32x4 __attribute__((ext_vector_type(4)));
typedef unsigned short u16x4 __attribute__((ext_vector_type(4)));

// async global->LDS, 16B per lane; LDS dest must be wave-uniform base (+lane*16)
__device__ __forceinline__ void gload16(const void* g, void* l) {
  __builtin_amdgcn_global_load_lds((const __attribute__((address_space(1))) void*)g,
                                   (__attribute__((address_space(3))) void*)l, 16, 0, 0);
}

__device__ __forceinline__ unsigned short bf16b(float f) {
  return __builtin_bit_cast(unsigned short, (bf16_t)f);
}
__device__ __forceinline__ float bf16f(unsigned short u) {
  return (float)__builtin_bit_cast(bf16_t, u);
}

// ---------------- f32 -> bf16 convert (x, w_qkv, w_out) ----------------
__global__ __launch_bounds__(256) void k_convert(const float* __restrict__ x,
                                                 const float* __restrict__ wqkv,
                                                 const float* __restrict__ wout,
                                                 unsigned short* __restrict__ xb,
                                                 unsigned short* __restrict__ wqb,
                                                 unsigned short* __restrict__ wob) {
  const int n1 = BB * SS * DD / 4;     // 1572864 float4s
  const int n2 = n1 + TD * DD / 4;     // +442368
  const int n3 = n2 + DD * DD / 4;     // +147456
  int i = blockIdx.x * 256 + threadIdx.x;
  if (i >= n3) return;
  const float4* s;
  unsigned short* d;
  int j;
  if (i < n1)      { s = (const float4*)x;    d = xb;  j = i; }
  else if (i < n2) { s = (const float4*)wqkv; d = wqb; j = i - n1; }
  else             { s = (const float4*)wout; d = wob; j = i - n2; }
  float4 v = s[j];
  u16x4 o;
  o[0] = bf16b(v.x); o[1] = bf16b(v.y); o[2] = bf16b(v.z); o[3] = bf16b(v.w);
  *(u16x4*)(d + (size_t)j * 4) = o;
}

// ---------------- 128x128 bf16 GEMM, C = A * Bw^T ----------------
// A: [M][K] bf16 row-major, Bw: [N][K] bf16 row-major (both K-contiguous).
// EPI==0: QKV epilogue (RoPE on q,k; q,k -> [B,H,S,64]; v -> [B,H,64,S] transposed)
// EPI==1: plain f32 store to Cf [M][N]
template <int EPI>
__global__ __launch_bounds__(256) void k_gemm(const unsigned short* __restrict__ A,
                                              const unsigned short* __restrict__ Bw,
                                              float* __restrict__ Cf,
                                              unsigned short* __restrict__ qb,
                                              unsigned short* __restrict__ kb,
                                              unsigned short* __restrict__ vtb,
                                              int K, int N) {
  __shared__ char smem[32768];
  char* As = smem;            // [128][64] bf16, XOR-swizzled (byte ^= (row&7)<<4)
  char* Bs = smem + 16384;    // same
  const int tid = threadIdx.x;
  const int lane = tid & 63;
  const int w = tid >> 6, wm = w >> 1, wn = w & 1;
  const int m0 = blockIdx.x * 128, n0 = blockIdx.y * 128;

  const f32x4 zero4 = {0.f, 0.f, 0.f, 0.f};
  f32x4 acc[4][4];
#pragma unroll
  for (int a = 0; a < 4; ++a)
#pragma unroll
    for (int c = 0; c < 4; ++c) acc[a][c] = zero4;

  const int srow = tid >> 3;        // staging row (per instr chunk of 32 rows)
  const int sslot = tid & 7;        // 16B slot within 128B row
  const int wbase = (tid & 192) * 16;  // wave-uniform LDS byte base

  for (int k0 = 0; k0 < K; k0 += 64) {
#pragma unroll
    for (int i = 0; i < 4; ++i) {   // A tile: 128 rows x 64 k (16KB)
      int row = i * 32 + srow;
      int kg = sslot ^ (row & 7);   // pre-swizzled source slot -> linear dest lands swizzled
      gload16(A + (size_t)(m0 + row) * K + (k0 + kg * 8), As + i * 4096 + wbase);
    }
#pragma unroll
    for (int i = 0; i < 4; ++i) {
      int row = i * 32 + srow;
      int kg = sslot ^ (row & 7);
      gload16(Bw + (size_t)(n0 + row) * K + (k0 + kg * 8), Bs + i * 4096 + wbase);
    }
    __syncthreads();
#pragma unroll
    for (int kk = 0; kk < 2; ++kk) {
      bf16x8 af[4], bfr[4];
      int colb = (kk * 4 + (lane >> 4)) * 16;
#pragma unroll
      for (int mi = 0; mi < 4; ++mi) {
        int row = wm * 64 + mi * 16 + (lane & 15);
        af[mi] = *(const bf16x8*)(As + row * 128 + (colb ^ ((row & 7) << 4)));
      }
#pragma unroll
      for (int ni = 0; ni < 4; ++ni) {
        int row = wn * 64 + ni * 16 + (lane & 15);
        bfr[ni] = *(const bf16x8*)(Bs + row * 128 + (colb ^ ((row & 7) << 4)));
      }
#pragma unroll
      for (int mi = 0; mi < 4; ++mi)
#pragma unroll
        for (int ni = 0; ni < 4; ++ni)
          acc[mi][ni] = __builtin_amdgcn_mfma_f32_16x16x32_bf16(af[mi], bfr[ni], acc[mi][ni], 0, 0, 0);
    }
    __syncthreads();
  }

  if (EPI == 1) {
#pragma unroll
    for (int mi = 0; mi < 4; ++mi)
#pragma unroll
      for (int ni = 0; ni < 4; ++ni) {
        int ng = n0 + wn * 64 + ni * 16 + (lane & 15);
#pragma unroll
        for (int r = 0; r < 4; ++r) {
          int mg = m0 + wm * 64 + mi * 16 + ((lane >> 4) << 2) + r;
          Cf[(size_t)mg * N + ng] = acc[mi][ni][r];
        }
      }
  } else {
#pragma unroll
    for (int ni = 0; ni < 4; ++ni) {
      int ng = n0 + wn * 64 + ni * 16 + (lane & 15);
      int part = ng / DD;           // 0=q 1=k 2=v (wave-uniform: 16 | 768)
      int c = ng % DD;
      int h = c >> 6, dh = c & 63;
      int i2 = dh >> 1;             // RoPE pair index
      float inv = __expf(-(float)i2 * (9.210340371976184f / 32.0f));  // 10000^(-2*i2/64)
#pragma unroll
      for (int mi = 0; mi < 4; ++mi)
#pragma unroll
        for (int r = 0; r < 4; ++r) {
          int mg = m0 + wm * 64 + mi * 16 + ((lane >> 4) << 2) + r;
          int b = mg >> 11, s = mg & (SS - 1);
          float v = acc[mi][ni][r];
          float other = __shfl_xor(v, 1);  // partner column (dh^1), same row
          if (part == 2) {
            // store V transposed: [B][H][64][S]
            vtb[((size_t)(b * HH + h) * 64 + dh) * SS + s] = bf16b(v);
          } else {
            float ang = (float)s * inv;
            float sn, cs;
            __sincosf(ang, &sn, &cs);
            float rr = (dh & 1) ? (other * sn + v * cs) : (v * cs - other * sn);
            unsigned short* dp = (part == 0) ? qb : kb;
            dp[((size_t)(b * HH + h) * SS + s) * 64 + dh] = bf16b(rr);
          }
        }
    }
  }
}

// ---------------- flash attention, causal, BQ=BKV=64, 4 waves ----------------
__global__ __launch_bounds__(256) void k_attn(const unsigned short* __restrict__ qb,
                                              const unsigned short* __restrict__ kb,
                                              const unsigned short* __restrict__ vtb,
                                              unsigned short* __restrict__ ob) {
  __shared__ char smem[32768];
  char* Qs = smem;           // [64][64] bf16 swizzled (rows = q)
  char* Ks = smem + 8192;    // [64][64] (rows = kv)
  char* Vs = smem + 16384;   // V^T [64][64] (rows = dh, cols = kv)
  const int tid = threadIdx.x, lane = tid & 63, w = tid >> 6;
  char* Ps = smem + 24576 + w * 2048;  // per-wave P [16][64]

  const int qt = (int)gridDim.x - 1 - (int)blockIdx.x;  // heavy tiles first
  const int h = blockIdx.y, b = blockIdx.z;
  const size_t bh = (size_t)(b * HH + h);
  const unsigned short* Qg = qb + bh * SS * 64;
  const unsigned short* Kg = kb + bh * SS * 64;
  const unsigned short* Vg = vtb + bh * 64 * SS;

  const int srow = tid >> 3, sslot = tid & 7;
  const int wbase = (tid & 192) * 16;

#pragma unroll
  for (int i = 0; i < 2; ++i) {
    int row = i * 32 + srow;
    int kg = sslot ^ (row & 7);
    gload16(Qg + (size_t)(qt * 64 + row) * 64 + kg * 8, Qs + i * 4096 + wbase);
  }
  __syncthreads();

  bf16x8 aq[2];  // this wave's 16 Q rows, kept in registers
  {
    int row = w * 16 + (lane & 15);
#pragma unroll
    for (int kk = 0; kk < 2; ++kk) {
      int colb = (kk * 4 + (lane >> 4)) * 16;
      aq[kk] = *(const bf16x8*)(Qs + row * 128 + (colb ^ ((row & 7) << 4)));
    }
  }

  const f32x4 zero4 = {0.f, 0.f, 0.f, 0.f};
  float mI[4], lI[4];
  f32x4 accO[4];
#pragma unroll
  for (int r = 0; r < 4; ++r) { mI[r] = -1e30f; lI[r] = 0.f; }
#pragma unroll
  for (int nf = 0; nf < 4; ++nf) accO[nf] = zero4;

  for (int kvt = 0; kvt <= qt; ++kvt) {
#pragma unroll
    for (int i = 0; i < 2; ++i) {
      int row = i * 32 + srow;
      int kg = sslot ^ (row & 7);
      gload16(Kg + (size_t)(kvt * 64 + row) * 64 + kg * 8, Ks + i * 4096 + wbase);
      gload16(Vg + (size_t)row * SS + (size_t)kvt * 64 + kg * 8, Vs + i * 4096 + wbase);
    }
    __syncthreads();

    // S = Q K^T
    f32x4 accS[4];
#pragma unroll
    for (int nf = 0; nf < 4; ++nf) accS[nf] = zero4;
#pragma unroll
    for (int nf = 0; nf < 4; ++nf) {
      int row = nf * 16 + (lane & 15);
#pragma unroll
      for (int kk = 0; kk < 2; ++kk) {
        int colb = (kk * 4 + (lane >> 4)) * 16;
        bf16x8 bk = *(const bf16x8*)(Ks + row * 128 + (colb ^ ((row & 7) << 4)));
        accS[nf] = __builtin_amdgcn_mfma_f32_16x16x32_bf16(aq[kk], bk, accS[nf], 0, 0, 0);
      }
    }

    // scale + causal mask
    float pbuf[4][4];
    const int cb0 = lane & 15;
    const int rb0 = qt * 64 + w * 16 + ((lane >> 4) << 2);
#pragma unroll
    for (int nf = 0; nf < 4; ++nf)
#pragma unroll
      for (int r = 0; r < 4; ++r) {
        float s = accS[nf][r] * 0.125f;
        if (kvt == qt && (kvt * 64 + nf * 16 + cb0) > (rb0 + r)) s = -1e30f;
        pbuf[nf][r] = s;
      }

    // online softmax (wave-parallel row reductions across the 16-lane col groups)
    float tmax[4];
#pragma unroll
    for (int r = 0; r < 4; ++r) {
      float t = fmaxf(fmaxf(pbuf[0][r], pbuf[1][r]), fmaxf(pbuf[2][r], pbuf[3][r]));
#pragma unroll
      for (int mk = 1; mk < 16; mk <<= 1) t = fmaxf(t, __shfl_xor(t, mk));
      tmax[r] = t;
    }
    float alpha[4], tsum[4];
#pragma unroll
    for (int r = 0; r < 4; ++r) {
      float mn = fmaxf(mI[r], tmax[r]);
      alpha[r] = __expf(mI[r] - mn);
      mI[r] = mn;
      tsum[r] = 0.f;
    }
    unsigned short pb[4][4];
#pragma unroll
    for (int nf = 0; nf < 4; ++nf)
#pragma unroll
      for (int r = 0; r < 4; ++r) {
        float p = __expf(pbuf[nf][r] - mI[r]);
        pb[nf][r] = bf16b(p);
        tsum[r] += bf16f(pb[nf][r]);  // sum the bf16-rounded weights -> exact normalization
      }
#pragma unroll
    for (int r = 0; r < 4; ++r) {
      float t = tsum[r];
#pragma unroll
      for (int mk = 1; mk < 16; mk <<= 1) t += __shfl_xor(t, mk);
      lI[r] = lI[r] * alpha[r] + t;
#pragma unroll
      for (int nf = 0; nf < 4; ++nf) accO[nf][r] = accO[nf][r] * alpha[r];
    }

    // write P (bf16) into per-wave LDS, swizzled
#pragma unroll
    for (int nf = 0; nf < 4; ++nf)
#pragma unroll
      for (int r = 0; r < 4; ++r) {
        int mrow = ((lane >> 4) << 2) + r;
        int cbyte = (nf * 16 + cb0) * 2;
        *(unsigned short*)(Ps + mrow * 128 + (cbyte ^ ((mrow & 7) << 4))) = pb[nf][r];
      }

    // O += P V   (B-operand from V^T rows = dh)
#pragma unroll
    for (int kk = 0; kk < 2; ++kk) {
      int prow = lane & 15;
      int pcolb = (kk * 4 + (lane >> 4)) * 16;
      bf16x8 pa = *(const bf16x8*)(Ps + prow * 128 + (pcolb ^ ((prow & 7) << 4)));
#pragma unroll
      for (int nf = 0; nf < 4; ++nf) {
        int vrow = nf * 16 + (lane & 15);
        bf16x8 bv = *(const bf16x8*)(Vs + vrow * 128 + (pcolb ^ ((vrow & 7) << 4)));
        accO[nf] = __builtin_amdgcn_mfma_f32_16x16x32_bf16(pa, bv, accO[nf], 0, 0, 0);
      }
    }
    __syncthreads();
  }

  // epilogue: normalize, store bf16 attn-out in [B][S][D] (head-interleaved)
#pragma unroll
  for (int nf = 0; nf < 4; ++nf) {
    int dh = nf * 16 + (lane & 15);
#pragma unroll
    for (int r = 0; r < 4; ++r) {
      int qrow = qt * 64 + w * 16 + ((lane >> 4) << 2) + r;
      float o = accO[nf][r] / lI[r];
      ob[((size_t)b * SS + qrow) * DD + h * 64 + dh] = bf16b(o);
    }
  }
}

extern "C" void kernel_launch(void* const* d_in, const int* in_sizes, int n_in,
                              void* d_out, int out_size, void* d_ws, size_t ws_size,
                              hipStream_t stream) {
  const float* x = (const float*)d_in[0];
  const float* wqkv = (const float*)d_in[1];
  const float* wout = (const float*)d_in[2];
  float* out = (float*)d_out;
  char* ws = (char*)d_ws;
  // workspace layout (67,633,152 bytes total)
  unsigned short* xb  = (unsigned short*)(ws);              // [8192][768] bf16
  unsigned short* wqb = (unsigned short*)(ws + 12582912);   // [2304][768]
  unsigned short* wob = (unsigned short*)(ws + 16121856);   // [768][768]
  unsigned short* qb  = (unsigned short*)(ws + 17301504);   // [B][H][S][64]
  unsigned short* kb  = (unsigned short*)(ws + 29884416);   // [B][H][S][64]
  unsigned short* vtb = (unsigned short*)(ws + 42467328);   // [B][H][64][S]
  unsigned short* ob  = (unsigned short*)(ws + 55050240);   // [8192][768]

  k_convert<<<8448, 256, 0, stream>>>(x, wqkv, wout, xb, wqb, wob);

  dim3 g1(64, 18);  // M/128 x (3D)/128
  k_gemm<0><<<g1, 256, 0, stream>>>(xb, wqb, nullptr, qb, kb, vtb, 768, 2304);

  dim3 ga(32, 12, 4);  // qtiles x H x B
  k_attn<<<ga, 256, 0, stream>>>(qb, kb, vtb, ob);

  dim3 g2(64, 6);  // M/128 x D/128
  k_gemm<1><<<g2, 256, 0, stream>>>(ob, wob, out, nullptr, nullptr, nullptr, 768, 768);
}

// Round 3
// 245.997 us; speedup vs baseline: 1.0299x; 1.0299x over previous
//
#include <hip/hip_runtime.h>
#include <hip/hip_bf16.h>

#define BB 4
#define SS 2048
#define DD 768
#define HH 12
#define TD 2304  // 3*D

typedef __bf16 bf16_t;
typedef bf16_t bf16x8 __attribute__((ext_vector_type(8)));
typedef float f32x4 __attribute__((ext_vector_type(4)));
typedef unsigned short u16x4 __attribute__((ext_vector_type(4)));

// async global->LDS, 16B per lane; LDS dest is wave-uniform base (+lane*16 by HW)
__device__ __forceinline__ void gload16(const void* g, void* l) {
  __builtin_amdgcn_global_load_lds((const __attribute__((address_space(1))) void*)g,
                                   (__attribute__((address_space(3))) void*)l, 16, 0, 0);
}

__device__ __forceinline__ unsigned short bf16b(float f) {
  return __builtin_bit_cast(unsigned short, (bf16_t)f);
}
__device__ __forceinline__ float bf16f(unsigned short u) {
  return (float)__builtin_bit_cast(bf16_t, u);
}

// ---------------- f32 -> bf16 convert (x, w_qkv, w_out) ----------------
__global__ __launch_bounds__(256) void k_convert(const float* __restrict__ x,
                                                 const float* __restrict__ wqkv,
                                                 const float* __restrict__ wout,
                                                 unsigned short* __restrict__ xb,
                                                 unsigned short* __restrict__ wqb,
                                                 unsigned short* __restrict__ wob) {
  const int n1 = BB * SS * DD / 4;     // 1572864 float4s
  const int n2 = n1 + TD * DD / 4;     // +442368
  const int n3 = n2 + DD * DD / 4;     // +147456
  int i = blockIdx.x * 256 + threadIdx.x;
  if (i >= n3) return;
  const float4* s;
  unsigned short* d;
  int j;
  if (i < n1)      { s = (const float4*)x;    d = xb;  j = i; }
  else if (i < n2) { s = (const float4*)wqkv; d = wqb; j = i - n1; }
  else             { s = (const float4*)wout; d = wob; j = i - n2; }
  float4 v = s[j];
  u16x4 o;
  o[0] = bf16b(v.x); o[1] = bf16b(v.y); o[2] = bf16b(v.z); o[3] = bf16b(v.w);
  *(u16x4*)(d + (size_t)j * 4) = o;
}

// ---------------- 128x128 bf16 GEMM, C = A * Bw^T ----------------
template <int EPI>
__global__ __launch_bounds__(256) void k_gemm(const unsigned short* __restrict__ A,
                                              const unsigned short* __restrict__ Bw,
                                              float* __restrict__ Cf,
                                              unsigned short* __restrict__ qb,
                                              unsigned short* __restrict__ kb,
                                              unsigned short* __restrict__ vtb,
                                              int K, int N) {
  __shared__ char smem[32768];
  char* As = smem;            // [128][64] bf16, XOR-swizzled (byte ^= (row&7)<<4)
  char* Bs = smem + 16384;    // same
  const int tid = threadIdx.x;
  const int lane = tid & 63;
  const int w = tid >> 6, wm = w >> 1, wn = w & 1;
  const int m0 = blockIdx.x * 128, n0 = blockIdx.y * 128;

  const f32x4 zero4 = {0.f, 0.f, 0.f, 0.f};
  f32x4 acc[4][4];
#pragma unroll
  for (int a = 0; a < 4; ++a)
#pragma unroll
    for (int c = 0; c < 4; ++c) acc[a][c] = zero4;

  const int srow = tid >> 3;
  const int sslot = tid & 7;
  const int wbase = (tid & 192) * 16;

  for (int k0 = 0; k0 < K; k0 += 64) {
#pragma unroll
    for (int i = 0; i < 4; ++i) {
      int row = i * 32 + srow;
      int kg = sslot ^ (row & 7);
      gload16(A + (size_t)(m0 + row) * K + (k0 + kg * 8), As + i * 4096 + wbase);
    }
#pragma unroll
    for (int i = 0; i < 4; ++i) {
      int row = i * 32 + srow;
      int kg = sslot ^ (row & 7);
      gload16(Bw + (size_t)(n0 + row) * K + (k0 + kg * 8), Bs + i * 4096 + wbase);
    }
    __syncthreads();
#pragma unroll
    for (int kk = 0; kk < 2; ++kk) {
      bf16x8 af[4], bfr[4];
      int colb = (kk * 4 + (lane >> 4)) * 16;
#pragma unroll
      for (int mi = 0; mi < 4; ++mi) {
        int row = wm * 64 + mi * 16 + (lane & 15);
        af[mi] = *(const bf16x8*)(As + row * 128 + (colb ^ ((row & 7) << 4)));
      }
#pragma unroll
      for (int ni = 0; ni < 4; ++ni) {
        int row = wn * 64 + ni * 16 + (lane & 15);
        bfr[ni] = *(const bf16x8*)(Bs + row * 128 + (colb ^ ((row & 7) << 4)));
      }
#pragma unroll
      for (int mi = 0; mi < 4; ++mi)
#pragma unroll
        for (int ni = 0; ni < 4; ++ni)
          acc[mi][ni] = __builtin_amdgcn_mfma_f32_16x16x32_bf16(af[mi], bfr[ni], acc[mi][ni], 0, 0, 0);
    }
    __syncthreads();
  }

  if (EPI == 1) {
#pragma unroll
    for (int mi = 0; mi < 4; ++mi)
#pragma unroll
      for (int ni = 0; ni < 4; ++ni) {
        int ng = n0 + wn * 64 + ni * 16 + (lane & 15);
#pragma unroll
        for (int r = 0; r < 4; ++r) {
          int mg = m0 + wm * 64 + mi * 16 + ((lane >> 4) << 2) + r;
          Cf[(size_t)mg * N + ng] = acc[mi][ni][r];
        }
      }
  } else {
#pragma unroll
    for (int ni = 0; ni < 4; ++ni) {
      int ng = n0 + wn * 64 + ni * 16 + (lane & 15);
      int part = ng / DD;           // 0=q 1=k 2=v (wave-uniform)
      int c = ng % DD;
      int h = c >> 6, dh = c & 63;
      int i2 = dh >> 1;
      float inv = __expf(-(float)i2 * (9.210340371976184f / 32.0f));  // 10000^(-2*i2/64)
#pragma unroll
      for (int mi = 0; mi < 4; ++mi)
#pragma unroll
        for (int r = 0; r < 4; ++r) {
          int mg = m0 + wm * 64 + mi * 16 + ((lane >> 4) << 2) + r;
          int b = mg >> 11, s = mg & (SS - 1);
          float v = acc[mi][ni][r];
          float other = __shfl_xor(v, 1);
          if (part == 2) {
            vtb[((size_t)(b * HH + h) * 64 + dh) * SS + s] = bf16b(v);
          } else {
            float ang = (float)s * inv;
            float sn, cs;
            __sincosf(ang, &sn, &cs);
            float rr = (dh & 1) ? (other * sn + v * cs) : (v * cs - other * sn);
            unsigned short* dp = (part == 0) ? qb : kb;
            dp[((size_t)(b * HH + h) * SS + s) * 64 + dh] = bf16b(rr);
          }
        }
    }
  }
}

// ---------------- flash attention, causal, BQ=128, BKV=64, 8 waves ----------------
// Double-buffered K/V with prefetch-before-compute (T3 minimal 2-phase).
__global__ __launch_bounds__(512, 4) void k_attn(const unsigned short* __restrict__ qb,
                                                 const unsigned short* __restrict__ kb,
                                                 const unsigned short* __restrict__ vtb,
                                                 unsigned short* __restrict__ ob) {
  __shared__ char smem[65536];
  char* Qs = smem;                    // [128 rows][128B] swizzled
  // K buffers at 16384 + buf*8192 ; V buffers at 32768 + buf*8192
  const int tid = threadIdx.x, lane = tid & 63, w = tid >> 6;
  char* Ps = smem + 49152 + w * 2048; // per-wave P [16][64] bf16 swizzled

  const int qt = 15 - (int)blockIdx.x;     // heavy tiles first
  const int h = blockIdx.y, b = blockIdx.z;
  const size_t bh = (size_t)(b * HH + h);
  const unsigned short* Qg = qb + bh * SS * 64;
  const unsigned short* Kg = kb + bh * SS * 64;
  const unsigned short* Vg = vtb + bh * 64 * SS;

  const int srow = tid >> 3, sslot = tid & 7;   // srow 0..63
  const int wbase = w * 1024;                   // wave-uniform LDS byte base

  // stage Q tile: 128 rows x 64 k (16KB), 2 chunks
#pragma unroll
  for (int i = 0; i < 2; ++i) {
    int row = i * 64 + srow;
    int kg = sslot ^ (row & 7);
    gload16(Qg + (size_t)(qt * 128 + row) * 64 + kg * 8, Qs + i * 8192 + wbase);
  }
  {  // stage K/V tile 0 into buffer 0
    int kg = sslot ^ (srow & 7);
    gload16(Kg + (size_t)srow * 64 + kg * 8, smem + 16384 + wbase);
    gload16(Vg + (size_t)srow * SS + kg * 8, smem + 32768 + wbase);
  }
  __syncthreads();

  bf16x8 aq[2];  // this wave's 16 Q rows
  {
    int row = w * 16 + (lane & 15);
#pragma unroll
    for (int kk = 0; kk < 2; ++kk) {
      int colb = (kk * 4 + (lane >> 4)) * 16;
      aq[kk] = *(const bf16x8*)(Qs + row * 128 + (colb ^ ((row & 7) << 4)));
    }
  }

  const f32x4 zero4 = {0.f, 0.f, 0.f, 0.f};
  float mI[4], lI[4];
  f32x4 accO[4];
#pragma unroll
  for (int r = 0; r < 4; ++r) { mI[r] = -1e30f; lI[r] = 0.f; }
#pragma unroll
  for (int nf = 0; nf < 4; ++nf) accO[nf] = zero4;

  const float SFT = 0.125f * 1.4426950408889634f;  // 1/sqrt(64) * log2(e)
  const int nkv = 2 * qt + 2;
  int cur = 0;

  for (int kvt = 0; kvt < nkv; ++kvt) {
    // prefetch next K/V tile into the other buffer (lands during compute below)
    if (kvt + 1 < nkv) {
      int kg = sslot ^ (srow & 7);
      gload16(Kg + (size_t)((kvt + 1) * 64 + srow) * 64 + kg * 8,
              smem + 16384 + (cur ^ 1) * 8192 + wbase);
      gload16(Vg + (size_t)srow * SS + (kvt + 1) * 64 + kg * 8,
              smem + 32768 + (cur ^ 1) * 8192 + wbase);
    }
    const char* Ks = smem + 16384 + cur * 8192;
    const char* Vs = smem + 32768 + cur * 8192;

    // S = Q K^T
    f32x4 accS[4];
#pragma unroll
    for (int nf = 0; nf < 4; ++nf) accS[nf] = zero4;
#pragma unroll
    for (int nf = 0; nf < 4; ++nf) {
      int row = nf * 16 + (lane & 15);
#pragma unroll
      for (int kk = 0; kk < 2; ++kk) {
        int colb = (kk * 4 + (lane >> 4)) * 16;
        bf16x8 bk = *(const bf16x8*)(Ks + row * 128 + (colb ^ ((row & 7) << 4)));
        accS[nf] = __builtin_amdgcn_mfma_f32_16x16x32_bf16(aq[kk], bk, accS[nf], 0, 0, 0);
      }
    }

    // scale (log2 domain) + causal mask
    float pbuf[4][4];
    const int cb0 = lane & 15;
    const int rb0 = qt * 128 + w * 16 + ((lane >> 4) << 2);
    const bool diag = (kvt >= 2 * qt);
#pragma unroll
    for (int nf = 0; nf < 4; ++nf)
#pragma unroll
      for (int r = 0; r < 4; ++r) {
        float s = accS[nf][r] * SFT;
        if (diag && (kvt * 64 + nf * 16 + cb0) > (rb0 + r)) s = -1e30f;
        pbuf[nf][r] = s;
      }

    // online softmax (base-2), wave-parallel row reductions
    float tmax[4];
#pragma unroll
    for (int r = 0; r < 4; ++r) {
      float t = fmaxf(fmaxf(pbuf[0][r], pbuf[1][r]), fmaxf(pbuf[2][r], pbuf[3][r]));
#pragma unroll
      for (int mk = 1; mk < 16; mk <<= 1) t = fmaxf(t, __shfl_xor(t, mk));
      tmax[r] = t;
    }
    float alpha[4], tsum[4];
#pragma unroll
    for (int r = 0; r < 4; ++r) {
      float mn = fmaxf(mI[r], tmax[r]);
      alpha[r] = exp2f(mI[r] - mn);
      mI[r] = mn;
      tsum[r] = 0.f;
    }
    unsigned short pb[4][4];
#pragma unroll
    for (int nf = 0; nf < 4; ++nf)
#pragma unroll
      for (int r = 0; r < 4; ++r) {
        float p = exp2f(pbuf[nf][r] - mI[r]);
        pb[nf][r] = bf16b(p);
        tsum[r] += bf16f(pb[nf][r]);  // sum bf16-rounded weights -> exact normalization
      }
#pragma unroll
    for (int r = 0; r < 4; ++r) {
      float t = tsum[r];
#pragma unroll
      for (int mk = 1; mk < 16; mk <<= 1) t += __shfl_xor(t, mk);
      lI[r] = lI[r] * alpha[r] + t;
#pragma unroll
      for (int nf = 0; nf < 4; ++nf) accO[nf][r] = accO[nf][r] * alpha[r];
    }

    // write P (bf16) into per-wave LDS, swizzled
#pragma unroll
    for (int nf = 0; nf < 4; ++nf)
#pragma unroll
      for (int r = 0; r < 4; ++r) {
        int mrow = ((lane >> 4) << 2) + r;
        int cbyte = (nf * 16 + cb0) * 2;
        *(unsigned short*)(Ps + mrow * 128 + (cbyte ^ ((mrow & 7) << 4))) = pb[nf][r];
      }

    // O += P V   (B-operand from V^T rows = dh)
#pragma unroll
    for (int kk = 0; kk < 2; ++kk) {
      int prow = lane & 15;
      int pcolb = (kk * 4 + (lane >> 4)) * 16;
      bf16x8 pa = *(const bf16x8*)(Ps + prow * 128 + (pcolb ^ ((prow & 7) << 4)));
#pragma unroll
      for (int nf = 0; nf < 4; ++nf) {
        int vrow = nf * 16 + (lane & 15);
        bf16x8 bv = *(const bf16x8*)(Vs + vrow * 128 + (pcolb ^ ((vrow & 7) << 4)));
        accO[nf] = __builtin_amdgcn_mfma_f32_16x16x32_bf16(pa, bv, accO[nf], 0, 0, 0);
      }
    }

    __syncthreads();  // vmcnt(0) drain lands AFTER compute -> prefetch latency hidden
    cur ^= 1;
  }

  // epilogue: normalize, store bf16 attn-out in [B][S][D]
#pragma unroll
  for (int nf = 0; nf < 4; ++nf) {
    int dh = nf * 16 + (lane & 15);
#pragma unroll
    for (int r = 0; r < 4; ++r) {
      int qrow = qt * 128 + w * 16 + ((lane >> 4) << 2) + r;
      float o = accO[nf][r] / lI[r];
      ob[((size_t)b * SS + qrow) * DD + h * 64 + dh] = bf16b(o);
    }
  }
}

extern "C" void kernel_launch(void* const* d_in, const int* in_sizes, int n_in,
                              void* d_out, int out_size, void* d_ws, size_t ws_size,
                              hipStream_t stream) {
  const float* x = (const float*)d_in[0];
  const float* wqkv = (const float*)d_in[1];
  const float* wout = (const float*)d_in[2];
  float* out = (float*)d_out;
  char* ws = (char*)d_ws;
  unsigned short* xb  = (unsigned short*)(ws);              // [8192][768] bf16
  unsigned short* wqb = (unsigned short*)(ws + 12582912);   // [2304][768]
  unsigned short* wob = (unsigned short*)(ws + 16121856);   // [768][768]
  unsigned short* qb  = (unsigned short*)(ws + 17301504);   // [B][H][S][64]
  unsigned short* kb  = (unsigned short*)(ws + 29884416);   // [B][H][S][64]
  unsigned short* vtb = (unsigned short*)(ws + 42467328);   // [B][H][64][S]
  unsigned short* ob  = (unsigned short*)(ws + 55050240);   // [8192][768]

  k_convert<<<8448, 256, 0, stream>>>(x, wqkv, wout, xb, wqb, wob);

  dim3 g1(64, 18);  // M/128 x (3D)/128
  k_gemm<0><<<g1, 256, 0, stream>>>(xb, wqb, nullptr, qb, kb, vtb, 768, 2304);

  dim3 ga(16, 12, 4);  // qtiles(128) x H x B
  k_attn<<<ga, 512, 0, stream>>>(qb, kb, vtb, ob);

  dim3 g2(64, 6);  // M/128 x D/128
  k_gemm<1><<<g2, 256, 0, stream>>>(ob, wob, out, nullptr, nullptr, nullptr, 768, 768);
}

// Round 4
// 210.558 us; speedup vs baseline: 1.2032x; 1.1683x over previous
//
#include <hip/hip_runtime.h>
#include <hip/hip_bf16.h>

#define BB 4
#define SS 2048
#define DD 768
#define HH 12
#define TD 2304  // 3*D

typedef __bf16 bf16_t;
typedef bf16_t bf16x8 __attribute__((ext_vector_type(8)));
typedef float f32x4 __attribute__((ext_vector_type(4)));
typedef unsigned short u16x4 __attribute__((ext_vector_type(4)));

// async global->LDS, 16B per lane; LDS dest is wave-uniform base (+lane*16 by HW)
__device__ __forceinline__ void gload16(const void* g, void* l) {
  __builtin_amdgcn_global_load_lds((const __attribute__((address_space(1))) void*)g,
                                   (__attribute__((address_space(3))) void*)l, 16, 0, 0);
}

__device__ __forceinline__ unsigned short bf16b(float f) {
  return __builtin_bit_cast(unsigned short, (bf16_t)f);
}
__device__ __forceinline__ float bf16f(unsigned short u) {
  return (float)__builtin_bit_cast(bf16_t, u);
}

// ---------------- f32 -> bf16 convert (x, w_qkv, w_out) ----------------
__global__ __launch_bounds__(256) void k_convert(const float* __restrict__ x,
                                                 const float* __restrict__ wqkv,
                                                 const float* __restrict__ wout,
                                                 unsigned short* __restrict__ xb,
                                                 unsigned short* __restrict__ wqb,
                                                 unsigned short* __restrict__ wob) {
  const int n1 = BB * SS * DD / 4;     // 1572864 float4s
  const int n2 = n1 + TD * DD / 4;     // +442368
  const int n3 = n2 + DD * DD / 4;     // +147456
  int i = blockIdx.x * 256 + threadIdx.x;
  if (i >= n3) return;
  const float4* s;
  unsigned short* d;
  int j;
  if (i < n1)      { s = (const float4*)x;    d = xb;  j = i; }
  else if (i < n2) { s = (const float4*)wqkv; d = wqb; j = i - n1; }
  else             { s = (const float4*)wout; d = wob; j = i - n2; }
  float4 v = s[j];
  u16x4 o;
  o[0] = bf16b(v.x); o[1] = bf16b(v.y); o[2] = bf16b(v.z); o[3] = bf16b(v.w);
  *(u16x4*)(d + (size_t)j * 4) = o;
}

// ---------------- 128x128 bf16 GEMM, C = A * Bw^T ----------------
template <int EPI>
__global__ __launch_bounds__(256) void k_gemm(const unsigned short* __restrict__ A,
                                              const unsigned short* __restrict__ Bw,
                                              float* __restrict__ Cf,
                                              unsigned short* __restrict__ qb,
                                              unsigned short* __restrict__ kb,
                                              unsigned short* __restrict__ vtb,
                                              int K, int N) {
  __shared__ char smem[32768];
  char* As = smem;            // [128][64] bf16, XOR-swizzled (byte ^= (row&7)<<4)
  char* Bs = smem + 16384;    // same
  const int tid = threadIdx.x;
  const int lane = tid & 63;
  const int w = tid >> 6, wm = w >> 1, wn = w & 1;
  const int m0 = blockIdx.x * 128, n0 = blockIdx.y * 128;

  const f32x4 zero4 = {0.f, 0.f, 0.f, 0.f};
  f32x4 acc[4][4];
#pragma unroll
  for (int a = 0; a < 4; ++a)
#pragma unroll
    for (int c = 0; c < 4; ++c) acc[a][c] = zero4;

  const int srow = tid >> 3;
  const int sslot = tid & 7;
  const int wbase = (tid & 192) * 16;

  for (int k0 = 0; k0 < K; k0 += 64) {
#pragma unroll
    for (int i = 0; i < 4; ++i) {
      int row = i * 32 + srow;
      int kg = sslot ^ (row & 7);
      gload16(A + (size_t)(m0 + row) * K + (k0 + kg * 8), As + i * 4096 + wbase);
    }
#pragma unroll
    for (int i = 0; i < 4; ++i) {
      int row = i * 32 + srow;
      int kg = sslot ^ (row & 7);
      gload16(Bw + (size_t)(n0 + row) * K + (k0 + kg * 8), Bs + i * 4096 + wbase);
    }
    __syncthreads();
#pragma unroll
    for (int kk = 0; kk < 2; ++kk) {
      bf16x8 af[4], bfr[4];
      int colb = (kk * 4 + (lane >> 4)) * 16;
#pragma unroll
      for (int mi = 0; mi < 4; ++mi) {
        int row = wm * 64 + mi * 16 + (lane & 15);
        af[mi] = *(const bf16x8*)(As + row * 128 + (colb ^ ((row & 7) << 4)));
      }
#pragma unroll
      for (int ni = 0; ni < 4; ++ni) {
        int row = wn * 64 + ni * 16 + (lane & 15);
        bfr[ni] = *(const bf16x8*)(Bs + row * 128 + (colb ^ ((row & 7) << 4)));
      }
      __builtin_amdgcn_s_setprio(1);
#pragma unroll
      for (int mi = 0; mi < 4; ++mi)
#pragma unroll
        for (int ni = 0; ni < 4; ++ni)
          acc[mi][ni] = __builtin_amdgcn_mfma_f32_16x16x32_bf16(af[mi], bfr[ni], acc[mi][ni], 0, 0, 0);
      __builtin_amdgcn_s_setprio(0);
    }
    __syncthreads();
  }

  if (EPI == 1) {
#pragma unroll
    for (int mi = 0; mi < 4; ++mi)
#pragma unroll
      for (int ni = 0; ni < 4; ++ni) {
        int ng = n0 + wn * 64 + ni * 16 + (lane & 15);
#pragma unroll
        for (int r = 0; r < 4; ++r) {
          int mg = m0 + wm * 64 + mi * 16 + ((lane >> 4) << 2) + r;
          Cf[(size_t)mg * N + ng] = acc[mi][ni][r];
        }
      }
  } else {
#pragma unroll
    for (int ni = 0; ni < 4; ++ni) {
      int ng = n0 + wn * 64 + ni * 16 + (lane & 15);
      int part = ng / DD;           // 0=q 1=k 2=v (wave-uniform)
      int c = ng % DD;
      int h = c >> 6, dh = c & 63;
      int i2 = dh >> 1;
      float inv = __expf(-(float)i2 * (9.210340371976184f / 32.0f));  // 10000^(-2*i2/64)
#pragma unroll
      for (int mi = 0; mi < 4; ++mi)
#pragma unroll
        for (int r = 0; r < 4; ++r) {
          int mg = m0 + wm * 64 + mi * 16 + ((lane >> 4) << 2) + r;
          int b = mg >> 11, s = mg & (SS - 1);
          float v = acc[mi][ni][r];
          float other = __shfl_xor(v, 1);
          if (part == 2) {
            vtb[((size_t)(b * HH + h) * 64 + dh) * SS + s] = bf16b(v);
          } else {
            float ang = (float)s * inv;
            float sn, cs;
            __sincosf(ang, &sn, &cs);
            float rr = (dh & 1) ? (other * sn + v * cs) : (v * cs - other * sn);
            unsigned short* dp = (part == 0) ? qb : kb;
            dp[((size_t)(b * HH + h) * SS + s) * 64 + dh] = bf16b(rr);
          }
        }
    }
  }
}

// ---------------- flash attention, causal, BQ=128, BKV=64, 8 waves ----------------
// Double-buffered K/V prefetch; defer-max (THR) skips cross-lane trees + rescale
// on the common path; lI kept as per-lane partial, reduced once in epilogue.
__global__ __launch_bounds__(512, 4) void k_attn(const unsigned short* __restrict__ qb,
                                                 const unsigned short* __restrict__ kb,
                                                 const unsigned short* __restrict__ vtb,
                                                 unsigned short* __restrict__ ob) {
  __shared__ char smem[65536];
  char* Qs = smem;                    // [128 rows][128B] swizzled
  // K buffers at 16384 + buf*8192 ; V buffers at 32768 + buf*8192
  const int tid = threadIdx.x, lane = tid & 63, w = tid >> 6;
  char* Ps = smem + 49152 + w * 2048; // per-wave P [16][64] bf16 swizzled

  const int qt = 15 - (int)blockIdx.x;     // heavy tiles first
  const int h = blockIdx.y, b = blockIdx.z;
  const size_t bh = (size_t)(b * HH + h);
  const unsigned short* Qg = qb + bh * SS * 64;
  const unsigned short* Kg = kb + bh * SS * 64;
  const unsigned short* Vg = vtb + bh * 64 * SS;

  const int srow = tid >> 3, sslot = tid & 7;   // srow 0..63
  const int wbase = w * 1024;                   // wave-uniform LDS byte base

  // stage Q tile: 128 rows x 64 k (16KB), 2 chunks
#pragma unroll
  for (int i = 0; i < 2; ++i) {
    int row = i * 64 + srow;
    int kg = sslot ^ (row & 7);
    gload16(Qg + (size_t)(qt * 128 + row) * 64 + kg * 8, Qs + i * 8192 + wbase);
  }
  {  // stage K/V tile 0 into buffer 0
    int kg = sslot ^ (srow & 7);
    gload16(Kg + (size_t)srow * 64 + kg * 8, smem + 16384 + wbase);
    gload16(Vg + (size_t)srow * SS + kg * 8, smem + 32768 + wbase);
  }
  __syncthreads();

  bf16x8 aq[2];  // this wave's 16 Q rows
  {
    int row = w * 16 + (lane & 15);
#pragma unroll
    for (int kk = 0; kk < 2; ++kk) {
      int colb = (kk * 4 + (lane >> 4)) * 16;
      aq[kk] = *(const bf16x8*)(Qs + row * 128 + (colb ^ ((row & 7) << 4)));
    }
  }

  const f32x4 zero4 = {0.f, 0.f, 0.f, 0.f};
  float mI[4], lIp[4];   // running max (log2 domain), per-LANE partial sum
  f32x4 accO[4];
#pragma unroll
  for (int r = 0; r < 4; ++r) { mI[r] = -1e30f; lIp[r] = 0.f; }
#pragma unroll
  for (int nf = 0; nf < 4; ++nf) accO[nf] = zero4;

  const float SFT = 0.125f * 1.4426950408889634f;  // 1/sqrt(64) * log2(e)
  const float THR = 8.0f;                          // defer-max threshold (log2)
  const int nkv = 2 * qt + 2;
  int cur = 0;

  for (int kvt = 0; kvt < nkv; ++kvt) {
    // prefetch next K/V tile into the other buffer (lands during compute below)
    if (kvt + 1 < nkv) {
      int kg = sslot ^ (srow & 7);
      gload16(Kg + (size_t)((kvt + 1) * 64 + srow) * 64 + kg * 8,
              smem + 16384 + (cur ^ 1) * 8192 + wbase);
      gload16(Vg + (size_t)srow * SS + (kvt + 1) * 64 + kg * 8,
              smem + 32768 + (cur ^ 1) * 8192 + wbase);
    }
    const char* Ks = smem + 16384 + cur * 8192;
    const char* Vs = smem + 32768 + cur * 8192;

    // S = Q K^T
    f32x4 accS[4];
#pragma unroll
    for (int nf = 0; nf < 4; ++nf) accS[nf] = zero4;
#pragma unroll
    for (int nf = 0; nf < 4; ++nf) {
      int row = nf * 16 + (lane & 15);
#pragma unroll
      for (int kk = 0; kk < 2; ++kk) {
        int colb = (kk * 4 + (lane >> 4)) * 16;
        bf16x8 bk = *(const bf16x8*)(Ks + row * 128 + (colb ^ ((row & 7) << 4)));
        __builtin_amdgcn_s_setprio(1);
        accS[nf] = __builtin_amdgcn_mfma_f32_16x16x32_bf16(aq[kk], bk, accS[nf], 0, 0, 0);
        __builtin_amdgcn_s_setprio(0);
      }
    }

    // scale (log2 domain) + causal mask
    float pbuf[4][4];
    const int cb0 = lane & 15;
    const int rb0 = qt * 128 + w * 16 + ((lane >> 4) << 2);
    const bool diag = (kvt >= 2 * qt);
#pragma unroll
    for (int nf = 0; nf < 4; ++nf)
#pragma unroll
      for (int r = 0; r < 4; ++r) {
        float s = accS[nf][r] * SFT;
        if (diag && (kvt * 64 + nf * 16 + cb0) > (rb0 + r)) s = -1e30f;
        pbuf[nf][r] = s;
      }

    // per-lane partial max; skip trees + rescale unless some element exceeds mI+THR
    float pmax[4];
#pragma unroll
    for (int r = 0; r < 4; ++r)
      pmax[r] = fmaxf(fmaxf(pbuf[0][r], pbuf[1][r]), fmaxf(pbuf[2][r], pbuf[3][r]));
    bool need = (pmax[0] > mI[0] + THR) || (pmax[1] > mI[1] + THR) ||
                (pmax[2] > mI[2] + THR) || (pmax[3] > mI[3] + THR);
    if (__any(need)) {
#pragma unroll
      for (int r = 0; r < 4; ++r) {
        float t = pmax[r];
#pragma unroll
        for (int mk = 1; mk < 16; mk <<= 1) t = fmaxf(t, __shfl_xor(t, mk));
        float mn = fmaxf(mI[r], t);
        float al = exp2f(mI[r] - mn);
        mI[r] = mn;
        lIp[r] *= al;
#pragma unroll
        for (int nf = 0; nf < 4; ++nf) accO[nf][r] *= al;
      }
    }

    // P = 2^(S - mI), bf16; accumulate per-lane partial sum of the rounded weights
    unsigned short pb[4][4];
#pragma unroll
    for (int nf = 0; nf < 4; ++nf)
#pragma unroll
      for (int r = 0; r < 4; ++r) {
        float p = exp2f(pbuf[nf][r] - mI[r]);
        pb[nf][r] = bf16b(p);
        lIp[r] += bf16f(pb[nf][r]);
      }

    // write P (bf16) into per-wave LDS, swizzled
#pragma unroll
    for (int nf = 0; nf < 4; ++nf)
#pragma unroll
      for (int r = 0; r < 4; ++r) {
        int mrow = ((lane >> 4) << 2) + r;
        int cbyte = (nf * 16 + cb0) * 2;
        *(unsigned short*)(Ps + mrow * 128 + (cbyte ^ ((mrow & 7) << 4))) = pb[nf][r];
      }

    // O += P V   (B-operand from V^T rows = dh)
#pragma unroll
    for (int kk = 0; kk < 2; ++kk) {
      int prow = lane & 15;
      int pcolb = (kk * 4 + (lane >> 4)) * 16;
      bf16x8 pa = *(const bf16x8*)(Ps + prow * 128 + (pcolb ^ ((prow & 7) << 4)));
#pragma unroll
      for (int nf = 0; nf < 4; ++nf) {
        int vrow = nf * 16 + (lane & 15);
        bf16x8 bv = *(const bf16x8*)(Vs + vrow * 128 + (pcolb ^ ((vrow & 7) << 4)));
        __builtin_amdgcn_s_setprio(1);
        accO[nf] = __builtin_amdgcn_mfma_f32_16x16x32_bf16(pa, bv, accO[nf], 0, 0, 0);
        __builtin_amdgcn_s_setprio(0);
      }
    }

    __syncthreads();  // vmcnt(0) drain lands AFTER compute -> prefetch latency hidden
    cur ^= 1;
  }

  // epilogue: one tree-reduction of the per-lane partial sums, normalize, store
#pragma unroll
  for (int r = 0; r < 4; ++r) {
    float t = lIp[r];
#pragma unroll
    for (int mk = 1; mk < 16; mk <<= 1) t += __shfl_xor(t, mk);
    lIp[r] = t;
  }
#pragma unroll
  for (int nf = 0; nf < 4; ++nf) {
    int dh = nf * 16 + (lane & 15);
#pragma unroll
    for (int r = 0; r < 4; ++r) {
      int qrow = qt * 128 + w * 16 + ((lane >> 4) << 2) + r;
      float o = accO[nf][r] / lIp[r];
      ob[((size_t)b * SS + qrow) * DD + h * 64 + dh] = bf16b(o);
    }
  }
}

extern "C" void kernel_launch(void* const* d_in, const int* in_sizes, int n_in,
                              void* d_out, int out_size, void* d_ws, size_t ws_size,
                              hipStream_t stream) {
  const float* x = (const float*)d_in[0];
  const float* wqkv = (const float*)d_in[1];
  const float* wout = (const float*)d_in[2];
  float* out = (float*)d_out;
  char* ws = (char*)d_ws;
  unsigned short* xb  = (unsigned short*)(ws);              // [8192][768] bf16
  unsigned short* wqb = (unsigned short*)(ws + 12582912);   // [2304][768]
  unsigned short* wob = (unsigned short*)(ws + 16121856);   // [768][768]
  unsigned short* qb  = (unsigned short*)(ws + 17301504);   // [B][H][S][64]
  unsigned short* kb  = (unsigned short*)(ws + 29884416);   // [B][H][S][64]
  unsigned short* vtb = (unsigned short*)(ws + 42467328);   // [B][H][64][S]
  unsigned short* ob  = (unsigned short*)(ws + 55050240);   // [8192][768]

  k_convert<<<8448, 256, 0, stream>>>(x, wqkv, wout, xb, wqb, wob);

  dim3 g1(64, 18);  // M/128 x (3D)/128
  k_gemm<0><<<g1, 256, 0, stream>>>(xb, wqb, nullptr, qb, kb, vtb, 768, 2304);

  dim3 ga(16, 12, 4);  // qtiles(128) x H x B
  k_attn<<<ga, 512, 0, stream>>>(qb, kb, vtb, ob);

  dim3 g2(64, 6);  // M/128 x D/128
  k_gemm<1><<<g2, 256, 0, stream>>>(ob, wob, out, nullptr, nullptr, nullptr, 768, 768);
}

// Round 5
// 183.894 us; speedup vs baseline: 1.3777x; 1.1450x over previous
//
#include <hip/hip_runtime.h>
#include <hip/hip_bf16.h>

#define BB 4
#define SS 2048
#define DD 768
#define HH 12
#define TD 2304  // 3*D

typedef __bf16 bf16_t;
typedef bf16_t bf16x8 __attribute__((ext_vector_type(8)));
typedef float f32x4 __attribute__((ext_vector_type(4)));
typedef unsigned short u16x4 __attribute__((ext_vector_type(4)));

// async global->LDS, 16B per lane; LDS dest is wave-uniform base (+lane*16 by HW)
__device__ __forceinline__ void gload16(const void* g, void* l) {
  __builtin_amdgcn_global_load_lds((const __attribute__((address_space(1))) void*)g,
                                   (__attribute__((address_space(3))) void*)l, 16, 0, 0);
}

__device__ __forceinline__ unsigned short bf16b(float f) {
  return __builtin_bit_cast(unsigned short, (bf16_t)f);
}
__device__ __forceinline__ float bf16f(unsigned short u) {
  return (float)__builtin_bit_cast(bf16_t, u);
}

// ---------------- f32 -> bf16 convert (x, w_qkv, w_out) ----------------
__global__ __launch_bounds__(256) void k_convert(const float* __restrict__ x,
                                                 const float* __restrict__ wqkv,
                                                 const float* __restrict__ wout,
                                                 unsigned short* __restrict__ xb,
                                                 unsigned short* __restrict__ wqb,
                                                 unsigned short* __restrict__ wob) {
  const int n1 = BB * SS * DD / 4;     // 1572864 float4s
  const int n2 = n1 + TD * DD / 4;     // +442368
  const int n3 = n2 + DD * DD / 4;     // +147456
  int i = blockIdx.x * 256 + threadIdx.x;
  if (i >= n3) return;
  const float4* s;
  unsigned short* d;
  int j;
  if (i < n1)      { s = (const float4*)x;    d = xb;  j = i; }
  else if (i < n2) { s = (const float4*)wqkv; d = wqb; j = i - n1; }
  else             { s = (const float4*)wout; d = wob; j = i - n2; }
  float4 v = s[j];
  u16x4 o;
  o[0] = bf16b(v.x); o[1] = bf16b(v.y); o[2] = bf16b(v.z); o[3] = bf16b(v.w);
  *(u16x4*)(d + (size_t)j * 4) = o;
}

// ---------------- 128x128 bf16 GEMM, C = A * Bw^T ----------------
template <int EPI>
__global__ __launch_bounds__(256) void k_gemm(const unsigned short* __restrict__ A,
                                              const unsigned short* __restrict__ Bw,
                                              float* __restrict__ Cf,
                                              unsigned short* __restrict__ qb,
                                              unsigned short* __restrict__ kb,
                                              unsigned short* __restrict__ vtb,
                                              int K, int N) {
  __shared__ char smem[32768];
  char* As = smem;            // [128][64] bf16, XOR-swizzled (byte ^= (row&7)<<4)
  char* Bs = smem + 16384;    // same
  const int tid = threadIdx.x;
  const int lane = tid & 63;
  const int w = tid >> 6, wm = w >> 1, wn = w & 1;
  const int m0 = blockIdx.x * 128, n0 = blockIdx.y * 128;

  const f32x4 zero4 = {0.f, 0.f, 0.f, 0.f};
  f32x4 acc[4][4];
#pragma unroll
  for (int a = 0; a < 4; ++a)
#pragma unroll
    for (int c = 0; c < 4; ++c) acc[a][c] = zero4;

  const int srow = tid >> 3;
  const int sslot = tid & 7;
  const int wbase = (tid & 192) * 16;

  for (int k0 = 0; k0 < K; k0 += 64) {
#pragma unroll
    for (int i = 0; i < 4; ++i) {
      int row = i * 32 + srow;
      int kg = sslot ^ (row & 7);
      gload16(A + (size_t)(m0 + row) * K + (k0 + kg * 8), As + i * 4096 + wbase);
    }
#pragma unroll
    for (int i = 0; i < 4; ++i) {
      int row = i * 32 + srow;
      int kg = sslot ^ (row & 7);
      gload16(Bw + (size_t)(n0 + row) * K + (k0 + kg * 8), Bs + i * 4096 + wbase);
    }
    __syncthreads();
#pragma unroll
    for (int kk = 0; kk < 2; ++kk) {
      bf16x8 af[4], bfr[4];
      int colb = (kk * 4 + (lane >> 4)) * 16;
#pragma unroll
      for (int mi = 0; mi < 4; ++mi) {
        int row = wm * 64 + mi * 16 + (lane & 15);
        af[mi] = *(const bf16x8*)(As + row * 128 + (colb ^ ((row & 7) << 4)));
      }
#pragma unroll
      for (int ni = 0; ni < 4; ++ni) {
        int row = wn * 64 + ni * 16 + (lane & 15);
        bfr[ni] = *(const bf16x8*)(Bs + row * 128 + (colb ^ ((row & 7) << 4)));
      }
      __builtin_amdgcn_s_setprio(1);
#pragma unroll
      for (int mi = 0; mi < 4; ++mi)
#pragma unroll
        for (int ni = 0; ni < 4; ++ni)
          acc[mi][ni] = __builtin_amdgcn_mfma_f32_16x16x32_bf16(af[mi], bfr[ni], acc[mi][ni], 0, 0, 0);
      __builtin_amdgcn_s_setprio(0);
    }
    __syncthreads();
  }

  if (EPI == 1) {
#pragma unroll
    for (int mi = 0; mi < 4; ++mi)
#pragma unroll
      for (int ni = 0; ni < 4; ++ni) {
        int ng = n0 + wn * 64 + ni * 16 + (lane & 15);
#pragma unroll
        for (int r = 0; r < 4; ++r) {
          int mg = m0 + wm * 64 + mi * 16 + ((lane >> 4) << 2) + r;
          Cf[(size_t)mg * N + ng] = acc[mi][ni][r];
        }
      }
  } else {
    const float SFT = 0.125f * 1.4426950408889634f;  // fold 1/sqrt(DH)*log2e into Q
#pragma unroll
    for (int ni = 0; ni < 4; ++ni) {
      int ng = n0 + wn * 64 + ni * 16 + (lane & 15);
      int part = ng / DD;           // 0=q 1=k 2=v (wave-uniform)
      int c = ng % DD;
      int h = c >> 6, dh = c & 63;
      int i2 = dh >> 1;
      float inv = __expf(-(float)i2 * (9.210340371976184f / 32.0f));  // 10000^(-2*i2/64)
#pragma unroll
      for (int mi = 0; mi < 4; ++mi)
#pragma unroll
        for (int r = 0; r < 4; ++r) {
          int mg = m0 + wm * 64 + mi * 16 + ((lane >> 4) << 2) + r;
          int b = mg >> 11, s = mg & (SS - 1);
          float v = acc[mi][ni][r];
          float other = __shfl_xor(v, 1);
          if (part == 2) {
            vtb[((size_t)(b * HH + h) * 64 + dh) * SS + s] = bf16b(v);
          } else {
            float ang = (float)s * inv;
            float sn, cs;
            __sincosf(ang, &sn, &cs);
            float rr = (dh & 1) ? (other * sn + v * cs) : (v * cs - other * sn);
            if (part == 0) rr *= SFT;
            unsigned short* dp = (part == 0) ? qb : kb;
            dp[((size_t)(b * HH + h) * SS + s) * 64 + dh] = bf16b(rr);
          }
        }
    }
  }
}

// ---------------- flash attention, causal, BQ=128, BKV=64, 8 waves ----------------
// Swapped QK^T (S^T orientation): lane owns one q-row -> scalar m/l state, no
// common-path shuffles, P packs to 4x ds_write_b64. Q LDS region aliased as P.
__global__ __launch_bounds__(512, 6) void k_attn(const unsigned short* __restrict__ qb,
                                                 const unsigned short* __restrict__ kb,
                                                 const unsigned short* __restrict__ vtb,
                                                 unsigned short* __restrict__ ob) {
  __shared__ char smem[49152];
  // Qs = smem [128 rows][128B] swizzled; wave w's rows [16w,16w+16) = [w*2048,+2048)
  // are read only by wave w, then reused as its P buffer.
  // K dbuf at 16384 + cur*8192 ; V dbuf at 32768 + cur*8192
  const int tid = threadIdx.x, lane = tid & 63, w = tid >> 6;
  char* Ps = smem + w * 2048;  // [16 q-rows][64 k] bf16, swizzled

  const int qt = 15 - (int)blockIdx.x;     // heavy tiles first
  const int h = blockIdx.y, b = blockIdx.z;
  const size_t bh = (size_t)(b * HH + h);
  const unsigned short* Qg = qb + bh * SS * 64;
  const unsigned short* Kg = kb + bh * SS * 64;
  const unsigned short* Vg = vtb + bh * 64 * SS;

  const int srow = tid >> 3, sslot = tid & 7;   // srow 0..63
  const int wbase = w * 1024;                   // wave-uniform LDS byte base

  // stage Q tile: 128 rows x 64 k (16KB), 2 chunks
#pragma unroll
  for (int i = 0; i < 2; ++i) {
    int row = i * 64 + srow;
    int kg = sslot ^ (row & 7);
    gload16(Qg + (size_t)(qt * 128 + row) * 64 + kg * 8, smem + i * 8192 + wbase);
  }
  {  // stage K/V tile 0 into buffer 0
    int kg = sslot ^ (srow & 7);
    gload16(Kg + (size_t)srow * 64 + kg * 8, smem + 16384 + wbase);
    gload16(Vg + (size_t)srow * SS + kg * 8, smem + 32768 + wbase);
  }
  __syncthreads();

  const int qrow_l = lane & 15;   // this lane's q-row (softmax layout)
  const int kgrp = lane >> 4;     // k subgroup 0..3

  bf16x8 aq[2];  // this wave's 16 Q rows (pre-scaled by 1/sqrt(DH)*log2e)
  {
    int row = w * 16 + qrow_l;
#pragma unroll
    for (int kk = 0; kk < 2; ++kk) {
      int colb = (kk * 4 + kgrp) * 16;
      aq[kk] = *(const bf16x8*)(smem + row * 128 + (colb ^ ((row & 7) << 4)));
    }
  }

  const f32x4 zero4 = {0.f, 0.f, 0.f, 0.f};
  float mI = -1e30f, lIp = 0.f;   // scalar running max / partial sum for q-row qrow_l
  f32x4 accO[4];
#pragma unroll
  for (int nf = 0; nf < 4; ++nf) accO[nf] = zero4;

  const float THR = 8.0f;   // defer-max threshold (log2 domain)
  const int nkv = 2 * qt + 2;
  int cur = 0;
  const int q_glob = qt * 128 + w * 16 + qrow_l;
  const int swz = (qrow_l & 7) << 4;

  for (int kvt = 0; kvt < nkv; ++kvt) {
    // prefetch next K/V tile into the other buffer (lands during compute below)
    if (kvt + 1 < nkv) {
      int kg = sslot ^ (srow & 7);
      gload16(Kg + (size_t)((kvt + 1) * 64 + srow) * 64 + kg * 8,
              smem + 16384 + (cur ^ 1) * 8192 + wbase);
      gload16(Vg + (size_t)srow * SS + (kvt + 1) * 64 + kg * 8,
              smem + 32768 + (cur ^ 1) * 8192 + wbase);
    }
    const char* Ks = smem + 16384 + cur * 8192;
    const char* Vs = smem + 32768 + cur * 8192;

    // S^T = K Q^T : D[k][q], k = nf*16 + kgrp*4 + r, q = qrow_l
    f32x4 accS[4];
#pragma unroll
    for (int nf = 0; nf < 4; ++nf) accS[nf] = zero4;
    __builtin_amdgcn_s_setprio(1);
#pragma unroll
    for (int nf = 0; nf < 4; ++nf) {
      int row = nf * 16 + qrow_l;
#pragma unroll
      for (int kk = 0; kk < 2; ++kk) {
        int colb = (kk * 4 + kgrp) * 16;
        bf16x8 bk = *(const bf16x8*)(Ks + row * 128 + (colb ^ ((row & 7) << 4)));
        accS[nf] = __builtin_amdgcn_mfma_f32_16x16x32_bf16(bk, aq[kk], accS[nf], 0, 0, 0);
      }
    }
    __builtin_amdgcn_s_setprio(0);

    // causal mask (diag tiles only) + per-lane max over this lane's 16 k-values
    const bool diag = (kvt >= 2 * qt);
    float pmax = -1e30f;
#pragma unroll
    for (int nf = 0; nf < 4; ++nf)
#pragma unroll
      for (int r = 0; r < 4; ++r) {
        float s = accS[nf][r];
        if (diag && (kvt * 64 + nf * 16 + kgrp * 4 + r) > q_glob) s = -1e30f;
        accS[nf][r] = s;
        pmax = fmaxf(pmax, s);
      }

    // defer-max: rare branch syncs max across the 4 lanes sharing this q-row
    if (__any(pmax > mI + THR)) {
      float t = pmax;
      t = fmaxf(t, __shfl_xor(t, 16));
      t = fmaxf(t, __shfl_xor(t, 32));
      float mn = fmaxf(mI, t);
      float al = exp2f(mI - mn);
      mI = mn;
      lIp *= al;
#pragma unroll
      for (int r = 0; r < 4; ++r) {
        float alq = __shfl(al, (kgrp << 2) + r);  // alpha for accO row (kgrp*4+r)
#pragma unroll
        for (int nf = 0; nf < 4; ++nf) accO[nf][r] *= alq;
      }
    }

    // P = 2^(S - mI); pack 4 consecutive k into one b64 LDS write; partial sum
#pragma unroll
    for (int nf = 0; nf < 4; ++nf) {
      float p0 = exp2f(accS[nf][0] - mI);
      float p1 = exp2f(accS[nf][1] - mI);
      float p2 = exp2f(accS[nf][2] - mI);
      float p3 = exp2f(accS[nf][3] - mI);
      lIp += (p0 + p1) + (p2 + p3);
      uint2 pk;
      pk.x = (unsigned)bf16b(p0) | ((unsigned)bf16b(p1) << 16);
      pk.y = (unsigned)bf16b(p2) | ((unsigned)bf16b(p3) << 16);
      *(uint2*)(Ps + qrow_l * 128 + ((nf * 32 + kgrp * 8) ^ swz)) = pk;
    }

    // O += P V   (A = P rows=q, B = V^T rows=dh)
#pragma unroll
    for (int kk = 0; kk < 2; ++kk) {
      int pcol = (kk * 4 + kgrp) * 16;
      bf16x8 pa = *(const bf16x8*)(Ps + qrow_l * 128 + (pcol ^ swz));
      __builtin_amdgcn_s_setprio(1);
#pragma unroll
      for (int nf = 0; nf < 4; ++nf) {
        int vrow = nf * 16 + qrow_l;
        bf16x8 bv = *(const bf16x8*)(Vs + vrow * 128 + (pcol ^ ((vrow & 7) << 4)));
        accO[nf] = __builtin_amdgcn_mfma_f32_16x16x32_bf16(pa, bv, accO[nf], 0, 0, 0);
      }
      __builtin_amdgcn_s_setprio(0);
    }

    __syncthreads();  // vmcnt(0) drain lands AFTER compute -> prefetch latency hidden
    cur ^= 1;
  }

  // epilogue: complete the row sums (2 shuffles), normalize, store
  lIp += __shfl_xor(lIp, 16);
  lIp += __shfl_xor(lIp, 32);
  float inv[4];
#pragma unroll
  for (int r = 0; r < 4; ++r)
    inv[r] = 1.0f / __shfl(lIp, (kgrp << 2) + r);  // l for accO row (kgrp*4+r)
#pragma unroll
  for (int nf = 0; nf < 4; ++nf) {
    int dh = nf * 16 + qrow_l;
#pragma unroll
    for (int r = 0; r < 4; ++r) {
      int qrow = qt * 128 + w * 16 + (kgrp << 2) + r;
      float o = accO[nf][r] * inv[r];
      ob[((size_t)b * SS + qrow) * DD + h * 64 + dh] = bf16b(o);
    }
  }
}

extern "C" void kernel_launch(void* const* d_in, const int* in_sizes, int n_in,
                              void* d_out, int out_size, void* d_ws, size_t ws_size,
                              hipStream_t stream) {
  const float* x = (const float*)d_in[0];
  const float* wqkv = (const float*)d_in[1];
  const float* wout = (const float*)d_in[2];
  float* out = (float*)d_out;
  char* ws = (char*)d_ws;
  unsigned short* xb  = (unsigned short*)(ws);              // [8192][768] bf16
  unsigned short* wqb = (unsigned short*)(ws + 12582912);   // [2304][768]
  unsigned short* wob = (unsigned short*)(ws + 16121856);   // [768][768]
  unsigned short* qb  = (unsigned short*)(ws + 17301504);   // [B][H][S][64]
  unsigned short* kb  = (unsigned short*)(ws + 29884416);   // [B][H][S][64]
  unsigned short* vtb = (unsigned short*)(ws + 42467328);   // [B][H][64][S]
  unsigned short* ob  = (unsigned short*)(ws + 55050240);   // [8192][768]

  k_convert<<<8448, 256, 0, stream>>>(x, wqkv, wout, xb, wqb, wob);

  dim3 g1(64, 18);  // M/128 x (3D)/128
  k_gemm<0><<<g1, 256, 0, stream>>>(xb, wqb, nullptr, qb, kb, vtb, 768, 2304);

  dim3 ga(16, 12, 4);  // qtiles(128) x H x B
  k_attn<<<ga, 512, 0, stream>>>(qb, kb, vtb, ob);

  dim3 g2(64, 6);  // M/128 x D/128
  k_gemm<1><<<g2, 256, 0, stream>>>(ob, wob, out, nullptr, nullptr, nullptr, 768, 768);
}

// Round 6
// 180.943 us; speedup vs baseline: 1.4001x; 1.0163x over previous
//
#include <hip/hip_runtime.h>
#include <hip/hip_bf16.h>

#define BB 4
#define SS 2048
#define DD 768
#define HH 12
#define TD 2304  // 3*D

typedef __bf16 bf16_t;
typedef bf16_t bf16x8 __attribute__((ext_vector_type(8)));
typedef float f32x4 __attribute__((ext_vector_type(4)));
typedef unsigned short u16x4 __attribute__((ext_vector_type(4)));

// async global->LDS, 16B per lane; LDS dest is wave-uniform base (+lane*16 by HW)
__device__ __forceinline__ void gload16(const void* g, void* l) {
  __builtin_amdgcn_global_load_lds((const __attribute__((address_space(1))) void*)g,
                                   (__attribute__((address_space(3))) void*)l, 16, 0, 0);
}

__device__ __forceinline__ unsigned short bf16b(float f) {
  return __builtin_bit_cast(unsigned short, (bf16_t)f);
}
__device__ __forceinline__ float bf16f(unsigned short u) {
  return (float)__builtin_bit_cast(bf16_t, u);
}

// ---------------- f32 -> bf16 convert (x, w_qkv, w_out) ----------------
__global__ __launch_bounds__(256) void k_convert(const float* __restrict__ x,
                                                 const float* __restrict__ wqkv,
                                                 const float* __restrict__ wout,
                                                 unsigned short* __restrict__ xb,
                                                 unsigned short* __restrict__ wqb,
                                                 unsigned short* __restrict__ wob) {
  const int n1 = BB * SS * DD / 4;     // 1572864 float4s
  const int n2 = n1 + TD * DD / 4;     // +442368
  const int n3 = n2 + DD * DD / 4;     // +147456
  int i = blockIdx.x * 256 + threadIdx.x;
  if (i >= n3) return;
  const float4* s;
  unsigned short* d;
  int j;
  if (i < n1)      { s = (const float4*)x;    d = xb;  j = i; }
  else if (i < n2) { s = (const float4*)wqkv; d = wqb; j = i - n1; }
  else             { s = (const float4*)wout; d = wob; j = i - n2; }
  float4 v = s[j];
  u16x4 o;
  o[0] = bf16b(v.x); o[1] = bf16b(v.y); o[2] = bf16b(v.z); o[3] = bf16b(v.w);
  *(u16x4*)(d + (size_t)j * 4) = o;
}

// ---------------- 128x128 bf16 GEMM, C = A * Bw^T ----------------
template <int EPI>
__global__ __launch_bounds__(256) void k_gemm(const unsigned short* __restrict__ A,
                                              const unsigned short* __restrict__ Bw,
                                              float* __restrict__ Cf,
                                              unsigned short* __restrict__ qb,
                                              unsigned short* __restrict__ kb,
                                              unsigned short* __restrict__ vtb,
                                              int K, int N) {
  __shared__ char smem[32768];
  char* As = smem;            // [128][64] bf16, XOR-swizzled (byte ^= (row&7)<<4)
  char* Bs = smem + 16384;    // same
  const int tid = threadIdx.x;
  const int lane = tid & 63;
  const int w = tid >> 6, wm = w >> 1, wn = w & 1;
  const int m0 = blockIdx.x * 128, n0 = blockIdx.y * 128;

  const f32x4 zero4 = {0.f, 0.f, 0.f, 0.f};
  f32x4 acc[4][4];
#pragma unroll
  for (int a = 0; a < 4; ++a)
#pragma unroll
    for (int c = 0; c < 4; ++c) acc[a][c] = zero4;

  const int srow = tid >> 3;
  const int sslot = tid & 7;
  const int wbase = (tid & 192) * 16;

  for (int k0 = 0; k0 < K; k0 += 64) {
#pragma unroll
    for (int i = 0; i < 4; ++i) {
      int row = i * 32 + srow;
      int kg = sslot ^ (row & 7);
      gload16(A + (size_t)(m0 + row) * K + (k0 + kg * 8), As + i * 4096 + wbase);
    }
#pragma unroll
    for (int i = 0; i < 4; ++i) {
      int row = i * 32 + srow;
      int kg = sslot ^ (row & 7);
      gload16(Bw + (size_t)(n0 + row) * K + (k0 + kg * 8), Bs + i * 4096 + wbase);
    }
    __syncthreads();
#pragma unroll
    for (int kk = 0; kk < 2; ++kk) {
      bf16x8 af[4], bfr[4];
      int colb = (kk * 4 + (lane >> 4)) * 16;
#pragma unroll
      for (int mi = 0; mi < 4; ++mi) {
        int row = wm * 64 + mi * 16 + (lane & 15);
        af[mi] = *(const bf16x8*)(As + row * 128 + (colb ^ ((row & 7) << 4)));
      }
#pragma unroll
      for (int ni = 0; ni < 4; ++ni) {
        int row = wn * 64 + ni * 16 + (lane & 15);
        bfr[ni] = *(const bf16x8*)(Bs + row * 128 + (colb ^ ((row & 7) << 4)));
      }
      __builtin_amdgcn_s_setprio(1);
#pragma unroll
      for (int mi = 0; mi < 4; ++mi)
#pragma unroll
        for (int ni = 0; ni < 4; ++ni)
          acc[mi][ni] = __builtin_amdgcn_mfma_f32_16x16x32_bf16(af[mi], bfr[ni], acc[mi][ni], 0, 0, 0);
      __builtin_amdgcn_s_setprio(0);
    }
    __syncthreads();
  }

  if (EPI == 1) {
#pragma unroll
    for (int mi = 0; mi < 4; ++mi)
#pragma unroll
      for (int ni = 0; ni < 4; ++ni) {
        int ng = n0 + wn * 64 + ni * 16 + (lane & 15);
#pragma unroll
        for (int r = 0; r < 4; ++r) {
          int mg = m0 + wm * 64 + mi * 16 + ((lane >> 4) << 2) + r;
          Cf[(size_t)mg * N + ng] = acc[mi][ni][r];
        }
      }
  } else {
    const float SFT = 0.125f * 1.4426950408889634f;  // fold 1/sqrt(DH)*log2e into Q
#pragma unroll
    for (int ni = 0; ni < 4; ++ni) {
      int ng = n0 + wn * 64 + ni * 16 + (lane & 15);
      int part = ng / DD;           // 0=q 1=k 2=v (wave-uniform)
      int c = ng % DD;
      int h = c >> 6, dh = c & 63;
      int i2 = dh >> 1;
      float inv = __expf(-(float)i2 * (9.210340371976184f / 32.0f));  // 10000^(-2*i2/64)
#pragma unroll
      for (int mi = 0; mi < 4; ++mi)
#pragma unroll
        for (int r = 0; r < 4; ++r) {
          int mg = m0 + wm * 64 + mi * 16 + ((lane >> 4) << 2) + r;
          int b = mg >> 11, s = mg & (SS - 1);
          float v = acc[mi][ni][r];
          float other = __shfl_xor(v, 1);
          if (part == 2) {
            vtb[((size_t)(b * HH + h) * 64 + dh) * SS + s] = bf16b(v);
          } else {
            float ang = (float)s * inv;
            float sn, cs;
            __sincosf(ang, &sn, &cs);
            float rr = (dh & 1) ? (other * sn + v * cs) : (v * cs - other * sn);
            if (part == 0) rr *= SFT;
            unsigned short* dp = (part == 0) ? qb : kb;
            dp[((size_t)(b * HH + h) * SS + s) * 64 + dh] = bf16b(rr);
          }
        }
    }
  }
}

// ---------------- flash attention, causal, BQ=64, BKV=64, 4 waves ----------------
// Swapped QK^T (S^T orientation), scalar m/l per lane, defer-max, P via b64 LDS
// writes into the aliased Q region. 40KB LDS -> 4 blocks/CU, 1536 blocks.
__global__ __launch_bounds__(256, 4) void k_attn(const unsigned short* __restrict__ qb,
                                                 const unsigned short* __restrict__ kb,
                                                 const unsigned short* __restrict__ vtb,
                                                 unsigned short* __restrict__ ob) {
  __shared__ char smem[40960];
  // [0,8192):      Q [64 rows][128B] swizzled; wave w's rows [16w,16w+16) =
  //                bytes [w*2048,+2048) are read only by wave w -> reused as P.
  // [8192,24576):  K double-buffer (8KB per tile)
  // [24576,40960): V^T double-buffer (8KB per tile)
  const int tid = threadIdx.x, lane = tid & 63, w = tid >> 6;
  char* Ps = smem + w * 2048;  // [16 q-rows][64 k] bf16, swizzled

  const int qt = 31 - (int)blockIdx.x;     // heavy tiles first
  const int h = blockIdx.y, b = blockIdx.z;
  const size_t bh = (size_t)(b * HH + h);
  const unsigned short* Qg = qb + bh * SS * 64;
  const unsigned short* Kg = kb + bh * SS * 64;
  const unsigned short* Vg = vtb + bh * 64 * SS;

  const int srow = tid >> 3, sslot = tid & 7;   // srow 0..31 (per 32-row chunk)
  const int wbase = w * 1024;                   // wave-uniform LDS byte base

  // stage Q tile: 64 rows x 64 k (8KB), 2 chunks of 32 rows
#pragma unroll
  for (int i = 0; i < 2; ++i) {
    int row = i * 32 + srow;
    int kg = sslot ^ (row & 7);
    gload16(Qg + (size_t)(qt * 64 + row) * 64 + kg * 8, smem + i * 4096 + wbase);
  }
  // stage K/V tile 0 into buffer 0
#pragma unroll
  for (int i = 0; i < 2; ++i) {
    int row = i * 32 + srow;
    int kg = sslot ^ (row & 7);
    gload16(Kg + (size_t)row * 64 + kg * 8, smem + 8192 + i * 4096 + wbase);
    gload16(Vg + (size_t)row * SS + kg * 8, smem + 24576 + i * 4096 + wbase);
  }
  __syncthreads();

  const int qrow_l = lane & 15;   // this lane's q-row (softmax layout)
  const int kgrp = lane >> 4;     // k subgroup 0..3

  bf16x8 aq[2];  // this wave's 16 Q rows (pre-scaled by 1/sqrt(DH)*log2e)
  {
    int row = w * 16 + qrow_l;
#pragma unroll
    for (int kk = 0; kk < 2; ++kk) {
      int colb = (kk * 4 + kgrp) * 16;
      aq[kk] = *(const bf16x8*)(smem + row * 128 + (colb ^ ((row & 7) << 4)));
    }
  }

  const f32x4 zero4 = {0.f, 0.f, 0.f, 0.f};
  float mI = -1e30f, lIp = 0.f;   // scalar running max / partial sum for q-row qrow_l
  f32x4 accO[4];
#pragma unroll
  for (int nf = 0; nf < 4; ++nf) accO[nf] = zero4;

  const float THR = 8.0f;   // defer-max threshold (log2 domain)
  const int nkv = qt + 1;
  int cur = 0;
  const int q_glob = qt * 64 + w * 16 + qrow_l;
  const int swz = (qrow_l & 7) << 4;

  for (int kvt = 0; kvt < nkv; ++kvt) {
    // prefetch next K/V tile into the other buffer (lands during compute below)
    if (kvt + 1 < nkv) {
#pragma unroll
      for (int i = 0; i < 2; ++i) {
        int row = i * 32 + srow;
        int kg = sslot ^ (row & 7);
        gload16(Kg + (size_t)((kvt + 1) * 64 + row) * 64 + kg * 8,
                smem + 8192 + (cur ^ 1) * 8192 + i * 4096 + wbase);
        gload16(Vg + (size_t)row * SS + (kvt + 1) * 64 + kg * 8,
                smem + 24576 + (cur ^ 1) * 8192 + i * 4096 + wbase);
      }
    }
    const char* Ks = smem + 8192 + cur * 8192;
    const char* Vs = smem + 24576 + cur * 8192;

    // S^T = K Q^T : D[k][q], k = nf*16 + kgrp*4 + r, q = qrow_l
    f32x4 accS[4];
#pragma unroll
    for (int nf = 0; nf < 4; ++nf) accS[nf] = zero4;
    __builtin_amdgcn_s_setprio(1);
#pragma unroll
    for (int nf = 0; nf < 4; ++nf) {
      int row = nf * 16 + qrow_l;
#pragma unroll
      for (int kk = 0; kk < 2; ++kk) {
        int colb = (kk * 4 + kgrp) * 16;
        bf16x8 bk = *(const bf16x8*)(Ks + row * 128 + (colb ^ ((row & 7) << 4)));
        accS[nf] = __builtin_amdgcn_mfma_f32_16x16x32_bf16(bk, aq[kk], accS[nf], 0, 0, 0);
      }
    }
    __builtin_amdgcn_s_setprio(0);

    // causal mask (diag tile only) + per-lane max over this lane's 16 k-values
    const bool diag = (kvt == qt);
    float pmax = -1e30f;
#pragma unroll
    for (int nf = 0; nf < 4; ++nf)
#pragma unroll
      for (int r = 0; r < 4; ++r) {
        float s = accS[nf][r];
        if (diag && (kvt * 64 + nf * 16 + kgrp * 4 + r) > q_glob) s = -1e30f;
        accS[nf][r] = s;
        pmax = fmaxf(pmax, s);
      }

    // defer-max: rare branch syncs max across the 4 lanes sharing this q-row
    if (__any(pmax > mI + THR)) {
      float t = pmax;
      t = fmaxf(t, __shfl_xor(t, 16));
      t = fmaxf(t, __shfl_xor(t, 32));
      float mn = fmaxf(mI, t);
      float al = exp2f(mI - mn);
      mI = mn;
      lIp *= al;
#pragma unroll
      for (int r = 0; r < 4; ++r) {
        float alq = __shfl(al, (kgrp << 2) + r);  // alpha for accO row (kgrp*4+r)
#pragma unroll
        for (int nf = 0; nf < 4; ++nf) accO[nf][r] *= alq;
      }
    }

    // P = 2^(S - mI); pack 4 consecutive k into one b64 LDS write; partial sum
#pragma unroll
    for (int nf = 0; nf < 4; ++nf) {
      float p0 = exp2f(accS[nf][0] - mI);
      float p1 = exp2f(accS[nf][1] - mI);
      float p2 = exp2f(accS[nf][2] - mI);
      float p3 = exp2f(accS[nf][3] - mI);
      lIp += (p0 + p1) + (p2 + p3);
      uint2 pk;
      pk.x = (unsigned)bf16b(p0) | ((unsigned)bf16b(p1) << 16);
      pk.y = (unsigned)bf16b(p2) | ((unsigned)bf16b(p3) << 16);
      *(uint2*)(Ps + qrow_l * 128 + ((nf * 32 + kgrp * 8) ^ swz)) = pk;
    }

    // O += P V   (A = P rows=q, B = V^T rows=dh)
#pragma unroll
    for (int kk = 0; kk < 2; ++kk) {
      int pcol = (kk * 4 + kgrp) * 16;
      bf16x8 pa = *(const bf16x8*)(Ps + qrow_l * 128 + (pcol ^ swz));
      __builtin_amdgcn_s_setprio(1);
#pragma unroll
      for (int nf = 0; nf < 4; ++nf) {
        int vrow = nf * 16 + qrow_l;
        bf16x8 bv = *(const bf16x8*)(Vs + vrow * 128 + (pcol ^ ((vrow & 7) << 4)));
        accO[nf] = __builtin_amdgcn_mfma_f32_16x16x32_bf16(pa, bv, accO[nf], 0, 0, 0);
      }
      __builtin_amdgcn_s_setprio(0);
    }

    __syncthreads();  // vmcnt(0) drain lands AFTER compute -> prefetch latency hidden
    cur ^= 1;
  }

  // epilogue: complete the row sums (2 shuffles), normalize, store
  lIp += __shfl_xor(lIp, 16);
  lIp += __shfl_xor(lIp, 32);
  float inv[4];
#pragma unroll
  for (int r = 0; r < 4; ++r)
    inv[r] = 1.0f / __shfl(lIp, (kgrp << 2) + r);  // l for accO row (kgrp*4+r)
#pragma unroll
  for (int nf = 0; nf < 4; ++nf) {
    int dh = nf * 16 + qrow_l;
#pragma unroll
    for (int r = 0; r < 4; ++r) {
      int qrow = qt * 64 + w * 16 + (kgrp << 2) + r;
      float o = accO[nf][r] * inv[r];
      ob[((size_t)b * SS + qrow) * DD + h * 64 + dh] = bf16b(o);
    }
  }
}

extern "C" void kernel_launch(void* const* d_in, const int* in_sizes, int n_in,
                              void* d_out, int out_size, void* d_ws, size_t ws_size,
                              hipStream_t stream) {
  const float* x = (const float*)d_in[0];
  const float* wqkv = (const float*)d_in[1];
  const float* wout = (const float*)d_in[2];
  float* out = (float*)d_out;
  char* ws = (char*)d_ws;
  unsigned short* xb  = (unsigned short*)(ws);              // [8192][768] bf16
  unsigned short* wqb = (unsigned short*)(ws + 12582912);   // [2304][768]
  unsigned short* wob = (unsigned short*)(ws + 16121856);   // [768][768]
  unsigned short* qb  = (unsigned short*)(ws + 17301504);   // [B][H][S][64]
  unsigned short* kb  = (unsigned short*)(ws + 29884416);   // [B][H][S][64]
  unsigned short* vtb = (unsigned short*)(ws + 42467328);   // [B][H][64][S]
  unsigned short* ob  = (unsigned short*)(ws + 55050240);   // [8192][768]

  k_convert<<<8448, 256, 0, stream>>>(x, wqkv, wout, xb, wqb, wob);

  dim3 g1(64, 18);  // M/128 x (3D)/128
  k_gemm<0><<<g1, 256, 0, stream>>>(xb, wqb, nullptr, qb, kb, vtb, 768, 2304);

  dim3 ga(32, 12, 4);  // qtiles(64) x H x B
  k_attn<<<ga, 256, 0, stream>>>(qb, kb, vtb, ob);

  dim3 g2(64, 6);  // M/128 x D/128
  k_gemm<1><<<g2, 256, 0, stream>>>(ob, wob, out, nullptr, nullptr, nullptr, 768, 768);
}

// Round 7
// 147.084 us; speedup vs baseline: 1.7224x; 1.2302x over previous
//
#include <hip/hip_runtime.h>
#include <hip/hip_bf16.h>

#define BB 4
#define SS 2048
#define DD 768
#define HH 12
#define TD 2304  // 3*D

typedef __bf16 bf16_t;
typedef bf16_t bf16x8 __attribute__((ext_vector_type(8)));
typedef float f32x4 __attribute__((ext_vector_type(4)));
typedef unsigned short u16x4 __attribute__((ext_vector_type(4)));

// async global->LDS, 16B per lane; LDS dest is wave-uniform base (+lane*16 by HW)
__device__ __forceinline__ void gload16(const void* g, void* l) {
  __builtin_amdgcn_global_load_lds((const __attribute__((address_space(1))) void*)g,
                                   (__attribute__((address_space(3))) void*)l, 16, 0, 0);
}

__device__ __forceinline__ unsigned short bf16b(float f) {
  return __builtin_bit_cast(unsigned short, (bf16_t)f);
}
__device__ __forceinline__ float bf16f(unsigned short u) {
  return (float)__builtin_bit_cast(bf16_t, u);
}

// ---------------- f32 -> bf16 convert (x, w_qkv, w_out) ----------------
__global__ __launch_bounds__(256) void k_convert(const float* __restrict__ x,
                                                 const float* __restrict__ wqkv,
                                                 const float* __restrict__ wout,
                                                 unsigned short* __restrict__ xb,
                                                 unsigned short* __restrict__ wqb,
                                                 unsigned short* __restrict__ wob) {
  const int n1 = BB * SS * DD / 4;     // 1572864 float4s
  const int n2 = n1 + TD * DD / 4;     // +442368
  const int n3 = n2 + DD * DD / 4;     // +147456
  int i = blockIdx.x * 256 + threadIdx.x;
  if (i >= n3) return;
  const float4* s;
  unsigned short* d;
  int j;
  if (i < n1)      { s = (const float4*)x;    d = xb;  j = i; }
  else if (i < n2) { s = (const float4*)wqkv; d = wqb; j = i - n1; }
  else             { s = (const float4*)wout; d = wob; j = i - n2; }
  float4 v = s[j];
  u16x4 o;
  o[0] = bf16b(v.x); o[1] = bf16b(v.y); o[2] = bf16b(v.z); o[3] = bf16b(v.w);
  *(u16x4*)(d + (size_t)j * 4) = o;
}

// ---------------- 128x128 bf16 GEMM, C = A * Bw^T ----------------
template <int EPI>
__global__ __launch_bounds__(256) void k_gemm(const unsigned short* __restrict__ A,
                                              const unsigned short* __restrict__ Bw,
                                              float* __restrict__ Cf,
                                              unsigned short* __restrict__ qb,
                                              unsigned short* __restrict__ kb,
                                              unsigned short* __restrict__ vtb,
                                              int K, int N) {
  __shared__ char smem[32768];
  char* As = smem;            // [128][64] bf16, XOR-swizzled (byte ^= (row&7)<<4)
  char* Bs = smem + 16384;    // same
  const int tid = threadIdx.x;
  const int lane = tid & 63;
  const int w = tid >> 6, wm = w >> 1, wn = w & 1;
  const int m0 = blockIdx.x * 128, n0 = blockIdx.y * 128;

  const f32x4 zero4 = {0.f, 0.f, 0.f, 0.f};
  f32x4 acc[4][4];
#pragma unroll
  for (int a = 0; a < 4; ++a)
#pragma unroll
    for (int c = 0; c < 4; ++c) acc[a][c] = zero4;

  const int srow = tid >> 3;
  const int sslot = tid & 7;
  const int wbase = (tid & 192) * 16;

  for (int k0 = 0; k0 < K; k0 += 64) {
#pragma unroll
    for (int i = 0; i < 4; ++i) {
      int row = i * 32 + srow;
      int kg = sslot ^ (row & 7);
      gload16(A + (size_t)(m0 + row) * K + (k0 + kg * 8), As + i * 4096 + wbase);
    }
#pragma unroll
    for (int i = 0; i < 4; ++i) {
      int row = i * 32 + srow;
      int kg = sslot ^ (row & 7);
      gload16(Bw + (size_t)(n0 + row) * K + (k0 + kg * 8), Bs + i * 4096 + wbase);
    }
    __syncthreads();
#pragma unroll
    for (int kk = 0; kk < 2; ++kk) {
      bf16x8 af[4], bfr[4];
      int colb = (kk * 4 + (lane >> 4)) * 16;
#pragma unroll
      for (int mi = 0; mi < 4; ++mi) {
        int row = wm * 64 + mi * 16 + (lane & 15);
        af[mi] = *(const bf16x8*)(As + row * 128 + (colb ^ ((row & 7) << 4)));
      }
#pragma unroll
      for (int ni = 0; ni < 4; ++ni) {
        int row = wn * 64 + ni * 16 + (lane & 15);
        bfr[ni] = *(const bf16x8*)(Bs + row * 128 + (colb ^ ((row & 7) << 4)));
      }
      __builtin_amdgcn_s_setprio(1);
#pragma unroll
      for (int mi = 0; mi < 4; ++mi)
#pragma unroll
        for (int ni = 0; ni < 4; ++ni)
          acc[mi][ni] = __builtin_amdgcn_mfma_f32_16x16x32_bf16(af[mi], bfr[ni], acc[mi][ni], 0, 0, 0);
      __builtin_amdgcn_s_setprio(0);
    }
    __syncthreads();
  }

  if (EPI == 1) {
#pragma unroll
    for (int mi = 0; mi < 4; ++mi)
#pragma unroll
      for (int ni = 0; ni < 4; ++ni) {
        int ng = n0 + wn * 64 + ni * 16 + (lane & 15);
#pragma unroll
        for (int r = 0; r < 4; ++r) {
          int mg = m0 + wm * 64 + mi * 16 + ((lane >> 4) << 2) + r;
          Cf[(size_t)mg * N + ng] = acc[mi][ni][r];
        }
      }
  } else {
    const float SFT = 0.125f * 1.4426950408889634f;  // fold 1/sqrt(DH)*log2e into Q
#pragma unroll
    for (int ni = 0; ni < 4; ++ni) {
      int ng = n0 + wn * 64 + ni * 16 + (lane & 15);
      int part = ng / DD;           // 0=q 1=k 2=v (wave-uniform)
      int c = ng % DD;
      int h = c >> 6, dh = c & 63;
      int i2 = dh >> 1;
      float inv = __expf(-(float)i2 * (9.210340371976184f / 32.0f));  // 10000^(-2*i2/64)
#pragma unroll
      for (int mi = 0; mi < 4; ++mi)
#pragma unroll
        for (int r = 0; r < 4; ++r) {
          int mg = m0 + wm * 64 + mi * 16 + ((lane >> 4) << 2) + r;
          int b = mg >> 11, s = mg & (SS - 1);
          float v = acc[mi][ni][r];
          float other = __shfl_xor(v, 1);
          if (part == 2) {
            vtb[((size_t)(b * HH + h) * 64 + dh) * SS + s] = bf16b(v);
          } else {
            float ang = (float)s * inv;
            float sn, cs;
            __sincosf(ang, &sn, &cs);
            float rr = (dh & 1) ? (other * sn + v * cs) : (v * cs - other * sn);
            if (part == 0) rr *= SFT;
            unsigned short* dp = (part == 0) ? qb : kb;
            dp[((size_t)(b * HH + h) * SS + s) * 64 + dh] = bf16b(rr);
          }
        }
    }
  }
}

// ---------------- flash attention, causal, BQ=64, 4 waves, paired Q-tiles ----------------
// Block bx handles qt=31-bx then qt=bx -> every block does exactly 33 kv-iters
// (perfect balance, 768 blocks = 3/CU). Swapped-S^T softmax, defer-max, row-sum
// via ones-MFMA (no epilogue shuffles).
__global__ __launch_bounds__(256, 4) void k_attn(const unsigned short* __restrict__ qb,
                                                 const unsigned short* __restrict__ kb,
                                                 const unsigned short* __restrict__ vtb,
                                                 unsigned short* __restrict__ ob) {
  __shared__ char smem[40960];
  // [0,8192):      Q [64 rows][128B] swizzled; wave w's rows reused as its P buffer
  // [8192,24576):  K double-buffer (8KB/tile)   [24576,40960): V^T double-buffer
  const int tid = threadIdx.x, lane = tid & 63, w = tid >> 6;
  char* Ps = smem + w * 2048;

  const int bx = blockIdx.x;               // 0..15
  const int h = blockIdx.y, b = blockIdx.z;
  const size_t bh = (size_t)(b * HH + h);
  const unsigned short* Qg = qb + bh * SS * 64;
  const unsigned short* Kg = kb + bh * SS * 64;
  const unsigned short* Vg = vtb + bh * 64 * SS;

  const int srow = tid >> 3, sslot = tid & 7;
  const int wbase = w * 1024;
  const int qrow_l = lane & 15;   // this lane's q-row (softmax layout)
  const int kgrp = lane >> 4;     // k subgroup 0..3
  const int swz = (qrow_l & 7) << 4;
  const f32x4 kz = {0.f, 0.f, 0.f, 0.f};
  const bf16_t oneb = (bf16_t)1.0f;
  const bf16x8 onev = {oneb, oneb, oneb, oneb, oneb, oneb, oneb, oneb};
  const float THR = 8.0f;

  int qt = 31 - bx;

  // initial stage: Q(qt) + K/V tile 0 -> buffer 0
#pragma unroll
  for (int i = 0; i < 2; ++i) {
    int row = i * 32 + srow;
    int kg = sslot ^ (row & 7);
    gload16(Qg + (size_t)(qt * 64 + row) * 64 + kg * 8, smem + i * 4096 + wbase);
    gload16(Kg + (size_t)row * 64 + kg * 8, smem + 8192 + i * 4096 + wbase);
    gload16(Vg + (size_t)row * SS + kg * 8, smem + 24576 + i * 4096 + wbase);
  }
  __syncthreads();

  int cur = 0;
  for (int pass = 0; pass < 2; ++pass) {
    bf16x8 aq[2];  // this wave's 16 Q rows (pre-scaled by 1/sqrt(DH)*log2e)
    {
      int row = w * 16 + qrow_l;
#pragma unroll
      for (int kk = 0; kk < 2; ++kk) {
        int colb = (kk * 4 + kgrp) * 16;
        aq[kk] = *(const bf16x8*)(smem + row * 128 + (colb ^ ((row & 7) << 4)));
      }
    }

    float mI = -1e30f;
    f32x4 accO[4], accL = kz;
#pragma unroll
    for (int nf = 0; nf < 4; ++nf) accO[nf] = kz;
    const int nkv = qt + 1;
    const int q_glob = qt * 64 + w * 16 + qrow_l;

    for (int kvt = 0; kvt < nkv; ++kvt) {
      // prefetch next K/V tile (or pass-1's tile 0 on pass-0's last iter)
      if (kvt + 1 < nkv) {
#pragma unroll
        for (int i = 0; i < 2; ++i) {
          int row = i * 32 + srow;
          int kg = sslot ^ (row & 7);
          gload16(Kg + (size_t)((kvt + 1) * 64 + row) * 64 + kg * 8,
                  smem + 8192 + (cur ^ 1) * 8192 + i * 4096 + wbase);
          gload16(Vg + (size_t)row * SS + (kvt + 1) * 64 + kg * 8,
                  smem + 24576 + (cur ^ 1) * 8192 + i * 4096 + wbase);
        }
      } else if (pass == 0) {
#pragma unroll
        for (int i = 0; i < 2; ++i) {
          int row = i * 32 + srow;
          int kg = sslot ^ (row & 7);
          gload16(Kg + (size_t)row * 64 + kg * 8,
                  smem + 8192 + (cur ^ 1) * 8192 + i * 4096 + wbase);
          gload16(Vg + (size_t)row * SS + kg * 8,
                  smem + 24576 + (cur ^ 1) * 8192 + i * 4096 + wbase);
        }
      }
      const char* Ks = smem + 8192 + cur * 8192;
      const char* Vs = smem + 24576 + cur * 8192;

      // S^T = K Q^T : D[k][q], k = nf*16 + kgrp*4 + r, q = qrow_l
      f32x4 accS[4];
      __builtin_amdgcn_s_setprio(1);
#pragma unroll
      for (int nf = 0; nf < 4; ++nf) {
        int row = nf * 16 + qrow_l;
        int rs = (row & 7) << 4;
        bf16x8 bk0 = *(const bf16x8*)(Ks + row * 128 + ((kgrp * 16) ^ rs));
        accS[nf] = __builtin_amdgcn_mfma_f32_16x16x32_bf16(bk0, aq[0], kz, 0, 0, 0);
        bf16x8 bk1 = *(const bf16x8*)(Ks + row * 128 + (((4 + kgrp) * 16) ^ rs));
        accS[nf] = __builtin_amdgcn_mfma_f32_16x16x32_bf16(bk1, aq[1], accS[nf], 0, 0, 0);
      }
      __builtin_amdgcn_s_setprio(0);

      // causal mask (diag tile only) + per-lane max over this lane's 16 k-values
      const bool diag = (kvt == qt);
      float pmax = -1e30f;
#pragma unroll
      for (int nf = 0; nf < 4; ++nf)
#pragma unroll
        for (int r = 0; r < 4; ++r) {
          float s = accS[nf][r];
          if (diag && (kvt * 64 + nf * 16 + kgrp * 4 + r) > q_glob) s = -1e30f;
          accS[nf][r] = s;
          pmax = fmaxf(pmax, s);
        }

      // defer-max: rare branch syncs max across the 4 lanes sharing this q-row
      if (__any(pmax > mI + THR)) {
        float t = pmax;
        t = fmaxf(t, __shfl_xor(t, 16));
        t = fmaxf(t, __shfl_xor(t, 32));
        float mn = fmaxf(mI, t);
        float al = exp2f(mI - mn);
        mI = mn;
#pragma unroll
        for (int r = 0; r < 4; ++r) {
          float alq = __shfl(al, (kgrp << 2) + r);  // alpha for accO/accL row
          accL[r] *= alq;
#pragma unroll
          for (int nf = 0; nf < 4; ++nf) accO[nf][r] *= alq;
        }
      }

      // P = 2^(S - mI); pack 4 consecutive k into one b64 LDS write
#pragma unroll
      for (int nf = 0; nf < 4; ++nf) {
        float p0 = exp2f(accS[nf][0] - mI);
        float p1 = exp2f(accS[nf][1] - mI);
        float p2 = exp2f(accS[nf][2] - mI);
        float p3 = exp2f(accS[nf][3] - mI);
        uint2 pk;
        pk.x = (unsigned)bf16b(p0) | ((unsigned)bf16b(p1) << 16);
        pk.y = (unsigned)bf16b(p2) | ((unsigned)bf16b(p3) << 16);
        *(uint2*)(Ps + qrow_l * 128 + ((nf * 32 + kgrp * 8) ^ swz)) = pk;
      }

      // O += P V ; row-sums via ones-MFMA (accL in accO layout)
#pragma unroll
      for (int kk = 0; kk < 2; ++kk) {
        int pcol = (kk * 4 + kgrp) * 16;
        bf16x8 pa = *(const bf16x8*)(Ps + qrow_l * 128 + (pcol ^ swz));
        __builtin_amdgcn_s_setprio(1);
#pragma unroll
        for (int nf = 0; nf < 4; ++nf) {
          int vrow = nf * 16 + qrow_l;
          bf16x8 bv = *(const bf16x8*)(Vs + vrow * 128 + (pcol ^ ((vrow & 7) << 4)));
          accO[nf] = __builtin_amdgcn_mfma_f32_16x16x32_bf16(pa, bv, accO[nf], 0, 0, 0);
        }
        accL = __builtin_amdgcn_mfma_f32_16x16x32_bf16(pa, onev, accL, 0, 0, 0);
        __builtin_amdgcn_s_setprio(0);
      }

      __syncthreads();  // vmcnt(0) drain lands AFTER compute -> prefetch hidden
      cur ^= 1;
    }

    if (pass == 0) {
      // stage pass-1's Q (qt=bx) into Q/P region; all waves are past the barrier
#pragma unroll
      for (int i = 0; i < 2; ++i) {
        int row = i * 32 + srow;
        int kg = sslot ^ (row & 7);
        gload16(Qg + (size_t)(bx * 64 + row) * 64 + kg * 8, smem + i * 4096 + wbase);
      }
    }

    // epilogue: accL holds row sums in accO layout -> no shuffles
    float inv[4];
#pragma unroll
    for (int r = 0; r < 4; ++r) inv[r] = 1.0f / accL[r];
#pragma unroll
    for (int nf = 0; nf < 4; ++nf) {
      int dh = nf * 16 + qrow_l;
#pragma unroll
      for (int r = 0; r < 4; ++r) {
        int qrow = qt * 64 + w * 16 + (kgrp << 2) + r;
        float o = accO[nf][r] * inv[r];
        ob[((size_t)b * SS + qrow) * DD + h * 64 + dh] = bf16b(o);
      }
    }

    if (pass == 0) {
      qt = bx;
      __syncthreads();  // drains Q stage; P region safe to reuse
    }
  }
}

extern "C" void kernel_launch(void* const* d_in, const int* in_sizes, int n_in,
                              void* d_out, int out_size, void* d_ws, size_t ws_size,
                              hipStream_t stream) {
  const float* x = (const float*)d_in[0];
  const float* wqkv = (const float*)d_in[1];
  const float* wout = (const float*)d_in[2];
  float* out = (float*)d_out;
  char* ws = (char*)d_ws;
  unsigned short* xb  = (unsigned short*)(ws);              // [8192][768] bf16
  unsigned short* wqb = (unsigned short*)(ws + 12582912);   // [2304][768]
  unsigned short* wob = (unsigned short*)(ws + 16121856);   // [768][768]
  unsigned short* qb  = (unsigned short*)(ws + 17301504);   // [B][H][S][64]
  unsigned short* kb  = (unsigned short*)(ws + 29884416);   // [B][H][S][64]
  unsigned short* vtb = (unsigned short*)(ws + 42467328);   // [B][H][64][S]
  unsigned short* ob  = (unsigned short*)(ws + 55050240);   // [8192][768]

  k_convert<<<8448, 256, 0, stream>>>(x, wqkv, wout, xb, wqb, wob);

  dim3 g1(64, 18);  // M/128 x (3D)/128
  k_gemm<0><<<g1, 256, 0, stream>>>(xb, wqb, nullptr, qb, kb, vtb, 768, 2304);

  dim3 ga(16, 12, 4);  // paired q-tiles x H x B  (uniform 33 iters/block)
  k_attn<<<ga, 256, 0, stream>>>(qb, kb, vtb, ob);

  dim3 g2(64, 6);  // M/128 x D/128
  k_gemm<1><<<g2, 256, 0, stream>>>(ob, wob, out, nullptr, nullptr, nullptr, 768, 768);
}

// Round 8
// 141.142 us; speedup vs baseline: 1.7950x; 1.0421x over previous
//
#include <hip/hip_runtime.h>
#include <hip/hip_bf16.h>

#define BB 4
#define SS 2048
#define DD 768
#define HH 12
#define TD 2304  // 3*D

typedef __bf16 bf16_t;
typedef bf16_t bf16x8 __attribute__((ext_vector_type(8)));
typedef float f32x4 __attribute__((ext_vector_type(4)));
typedef unsigned short u16x4 __attribute__((ext_vector_type(4)));

// async global->LDS, 16B per lane; LDS dest is wave-uniform base (+lane*16 by HW)
__device__ __forceinline__ void gload16(const void* g, void* l) {
  __builtin_amdgcn_global_load_lds((const __attribute__((address_space(1))) void*)g,
                                   (__attribute__((address_space(3))) void*)l, 16, 0, 0);
}

__device__ __forceinline__ unsigned short bf16b(float f) {
  return __builtin_bit_cast(unsigned short, (bf16_t)f);
}
__device__ __forceinline__ float bf16f(unsigned short u) {
  return (float)__builtin_bit_cast(bf16_t, u);
}

// ---------------- f32 -> bf16 convert (x, w_qkv, w_out) + RoPE trig table ----------------
__global__ __launch_bounds__(256) void k_convert(const float* __restrict__ x,
                                                 const float* __restrict__ wqkv,
                                                 const float* __restrict__ wout,
                                                 unsigned short* __restrict__ xb,
                                                 unsigned short* __restrict__ wqb,
                                                 unsigned short* __restrict__ wob,
                                                 float2* __restrict__ ttab) {
  const int n1 = BB * SS * DD / 4;     // 1572864 float4s
  const int n2 = n1 + TD * DD / 4;     // +442368
  const int n3 = n2 + DD * DD / 4;     // +147456 -> 2162688 = 8448*256
  int i = blockIdx.x * 256 + threadIdx.x;
  if (blockIdx.x >= 8448) {
    int idx = i - 8448 * 256;          // 0..65535 : s = idx>>5, i2 = idx&31
    if (idx < SS * 32) {
      int s = idx >> 5, i2 = idx & 31;
      float inv = __expf(-(float)i2 * (9.210340371976184f / 32.0f));
      float ang = (float)s * inv;
      float sn, cs;
      __sincosf(ang, &sn, &cs);
      ttab[idx] = make_float2(cs, sn);
    }
    return;
  }
  if (i >= n3) return;
  const float4* s;
  unsigned short* d;
  int j;
  if (i < n1)      { s = (const float4*)x;    d = xb;  j = i; }
  else if (i < n2) { s = (const float4*)wqkv; d = wqb; j = i - n1; }
  else             { s = (const float4*)wout; d = wob; j = i - n2; }
  float4 v = s[j];
  u16x4 o;
  o[0] = bf16b(v.x); o[1] = bf16b(v.y); o[2] = bf16b(v.z); o[3] = bf16b(v.w);
  *(u16x4*)(d + (size_t)j * 4) = o;
}

// ---------------- 128x128 bf16 GEMM, C = A * Bw^T ----------------
// EPI==0: QKV epilogue (RoPE from ttab, LDS-staged coalesced stores; v transposed)
// EPI==1: plain f32 store to Cf [M][N]
template <int EPI>
__global__ __launch_bounds__(256) void k_gemm(const unsigned short* __restrict__ A,
                                              const unsigned short* __restrict__ Bw,
                                              float* __restrict__ Cf,
                                              unsigned short* __restrict__ qb,
                                              unsigned short* __restrict__ kb,
                                              unsigned short* __restrict__ vtb,
                                              const float2* __restrict__ ttab,
                                              int K, int N) {
  __shared__ char smem[32768];
  char* As = smem;            // [128][64] bf16, XOR-swizzled (byte ^= (row&7)<<4)
  char* Bs = smem + 16384;    // same
  const int tid = threadIdx.x;
  const int lane = tid & 63;
  const int w = tid >> 6, wm = w >> 1, wn = w & 1;
  const int m0 = blockIdx.x * 128, n0 = blockIdx.y * 128;

  const f32x4 zero4 = {0.f, 0.f, 0.f, 0.f};
  f32x4 acc[4][4];
#pragma unroll
  for (int a = 0; a < 4; ++a)
#pragma unroll
    for (int c = 0; c < 4; ++c) acc[a][c] = zero4;

  const int srow = tid >> 3;
  const int sslot = tid & 7;
  const int wbase = (tid & 192) * 16;

  for (int k0 = 0; k0 < K; k0 += 64) {
#pragma unroll
    for (int i = 0; i < 4; ++i) {
      int row = i * 32 + srow;
      int kg = sslot ^ (row & 7);
      gload16(A + (size_t)(m0 + row) * K + (k0 + kg * 8), As + i * 4096 + wbase);
    }
#pragma unroll
    for (int i = 0; i < 4; ++i) {
      int row = i * 32 + srow;
      int kg = sslot ^ (row & 7);
      gload16(Bw + (size_t)(n0 + row) * K + (k0 + kg * 8), Bs + i * 4096 + wbase);
    }
    __syncthreads();
#pragma unroll
    for (int kk = 0; kk < 2; ++kk) {
      bf16x8 af[4], bfr[4];
      int colb = (kk * 4 + (lane >> 4)) * 16;
#pragma unroll
      for (int mi = 0; mi < 4; ++mi) {
        int row = wm * 64 + mi * 16 + (lane & 15);
        af[mi] = *(const bf16x8*)(As + row * 128 + (colb ^ ((row & 7) << 4)));
      }
#pragma unroll
      for (int ni = 0; ni < 4; ++ni) {
        int row = wn * 64 + ni * 16 + (lane & 15);
        bfr[ni] = *(const bf16x8*)(Bs + row * 128 + (colb ^ ((row & 7) << 4)));
      }
      __builtin_amdgcn_s_setprio(1);
#pragma unroll
      for (int mi = 0; mi < 4; ++mi)
#pragma unroll
        for (int ni = 0; ni < 4; ++ni)
          acc[mi][ni] = __builtin_amdgcn_mfma_f32_16x16x32_bf16(af[mi], bfr[ni], acc[mi][ni], 0, 0, 0);
      __builtin_amdgcn_s_setprio(0);
    }
    __syncthreads();
  }
  // NOTE: all waves passed the final barrier -> As/Bs reusable as C stage.

  if (EPI == 1) {
#pragma unroll
    for (int mi = 0; mi < 4; ++mi)
#pragma unroll
      for (int ni = 0; ni < 4; ++ni) {
        int ng = n0 + wn * 64 + ni * 16 + (lane & 15);
#pragma unroll
        for (int r = 0; r < 4; ++r) {
          int mg = m0 + wm * 64 + mi * 16 + ((lane >> 4) << 2) + r;
          Cf[(size_t)mg * N + ng] = acc[mi][ni][r];
        }
      }
  } else {
    const float SFT = 0.125f * 1.4426950408889634f;  // 1/sqrt(DH)*log2e folded into Q
    const int part = n0 / DD;          // 0=q 1=k 2=v (block-uniform: 128 | 768)
    const int h0 = (n0 % DD) >> 6;     // first of the 2 heads this block covers
    const int bB = m0 >> 11;           // batch (block-uniform: 128 | 2048)
    const int s0b = m0 & (SS - 1);     // base sequence position
    char* Cs = smem;                   // 32KB stage (As+Bs region)

    if (part < 2) {
      // ---- q/k: RoPE via table, row-major swizzled stage ----
#pragma unroll
      for (int mi = 0; mi < 4; ++mi) {
#pragma unroll
        for (int r = 0; r < 4; ++r) {
          int lr = wm * 64 + mi * 16 + ((lane >> 4) << 2) + r;
          const float2* tt = ttab + (size_t)(s0b + lr) * 32;
#pragma unroll
          for (int ni = 0; ni < 4; ++ni) {
            int lc = wn * 64 + ni * 16 + (lane & 15);
            int dh = lc & 63;
            float2 cs = tt[dh >> 1];
            float v = acc[mi][ni][r];
            float other = __shfl_xor(v, 1);
            float rr = (dh & 1) ? (other * cs.y + v * cs.x) : (v * cs.x - other * cs.y);
            if (part == 0) rr *= SFT;
            *(unsigned short*)(Cs + lr * 256 + ((lc * 2) ^ ((lr & 7) << 4))) = bf16b(rr);
          }
        }
      }
      __syncthreads();
      unsigned short* dp = (part == 0) ? qb : kb;
      const int j = tid & 15;
      const int head = j >> 3, dh0 = (j & 7) * 8;
#pragma unroll
      for (int t = 0; t < 8; ++t) {
        int lr = t * 16 + (tid >> 4);
        uint4 v16 = *(const uint4*)(Cs + lr * 256 + ((j * 16) ^ ((lr & 7) << 4)));
        *(uint4*)(dp + ((size_t)((bB * HH + h0 + head) * SS) + (s0b + lr)) * 64 + dh0) = v16;
      }
    } else {
      // ---- v: column-major swizzled stage -> transposed coalesced store ----
#pragma unroll
      for (int mi = 0; mi < 4; ++mi) {
#pragma unroll
        for (int r = 0; r < 4; ++r) {
          int lr = wm * 64 + mi * 16 + ((lane >> 4) << 2) + r;
#pragma unroll
          for (int ni = 0; ni < 4; ++ni) {
            int lc = wn * 64 + ni * 16 + (lane & 15);
            *(unsigned short*)(Cs + lc * 256 + ((lr * 2) ^ ((lc & 7) << 4))) =
                bf16b(acc[mi][ni][r]);
          }
        }
      }
      __syncthreads();
      const int j = tid & 15;
#pragma unroll
      for (int t = 0; t < 8; ++t) {
        int vrow = t * 16 + (tid >> 4);      // local col = head*64 + dh
        int head = vrow >> 6, dh = vrow & 63;
        uint4 v16 = *(const uint4*)(Cs + vrow * 256 + ((j * 16) ^ ((vrow & 7) << 4)));
        *(uint4*)(vtb + ((size_t)(bB * HH + h0 + head) * 64 + dh) * SS + s0b + j * 8) = v16;
      }
    }
  }
}

// ---------------- flash attention, causal, BQ=64, 4 waves, paired Q-tiles ----------------
__global__ __launch_bounds__(256, 4) void k_attn(const unsigned short* __restrict__ qb,
                                                 const unsigned short* __restrict__ kb,
                                                 const unsigned short* __restrict__ vtb,
                                                 unsigned short* __restrict__ ob) {
  __shared__ char smem[40960];
  const int tid = threadIdx.x, lane = tid & 63, w = tid >> 6;
  char* Ps = smem + w * 2048;

  const int bx = blockIdx.x;               // 0..15
  const int h = blockIdx.y, b = blockIdx.z;
  const size_t bh = (size_t)(b * HH + h);
  const unsigned short* Qg = qb + bh * SS * 64;
  const unsigned short* Kg = kb + bh * SS * 64;
  const unsigned short* Vg = vtb + bh * 64 * SS;

  const int srow = tid >> 3, sslot = tid & 7;
  const int wbase = w * 1024;
  const int qrow_l = lane & 15;
  const int kgrp = lane >> 4;
  const int swz = (qrow_l & 7) << 4;
  const f32x4 kz = {0.f, 0.f, 0.f, 0.f};
  const bf16_t oneb = (bf16_t)1.0f;
  const bf16x8 onev = {oneb, oneb, oneb, oneb, oneb, oneb, oneb, oneb};
  const float THR = 8.0f;

  int qt = 31 - bx;

#pragma unroll
  for (int i = 0; i < 2; ++i) {
    int row = i * 32 + srow;
    int kg = sslot ^ (row & 7);
    gload16(Qg + (size_t)(qt * 64 + row) * 64 + kg * 8, smem + i * 4096 + wbase);
    gload16(Kg + (size_t)row * 64 + kg * 8, smem + 8192 + i * 4096 + wbase);
    gload16(Vg + (size_t)row * SS + kg * 8, smem + 24576 + i * 4096 + wbase);
  }
  __syncthreads();

  int cur = 0;
  for (int pass = 0; pass < 2; ++pass) {
    bf16x8 aq[2];
    {
      int row = w * 16 + qrow_l;
#pragma unroll
      for (int kk = 0; kk < 2; ++kk) {
        int colb = (kk * 4 + kgrp) * 16;
        aq[kk] = *(const bf16x8*)(smem + row * 128 + (colb ^ ((row & 7) << 4)));
      }
    }

    float mI = -1e30f;
    f32x4 accO[4], accL = kz;
#pragma unroll
    for (int nf = 0; nf < 4; ++nf) accO[nf] = kz;
    const int nkv = qt + 1;
    const int q_glob = qt * 64 + w * 16 + qrow_l;

    for (int kvt = 0; kvt < nkv; ++kvt) {
      if (kvt + 1 < nkv) {
#pragma unroll
        for (int i = 0; i < 2; ++i) {
          int row = i * 32 + srow;
          int kg = sslot ^ (row & 7);
          gload16(Kg + (size_t)((kvt + 1) * 64 + row) * 64 + kg * 8,
                  smem + 8192 + (cur ^ 1) * 8192 + i * 4096 + wbase);
          gload16(Vg + (size_t)row * SS + (kvt + 1) * 64 + kg * 8,
                  smem + 24576 + (cur ^ 1) * 8192 + i * 4096 + wbase);
        }
      } else if (pass == 0) {
#pragma unroll
        for (int i = 0; i < 2; ++i) {
          int row = i * 32 + srow;
          int kg = sslot ^ (row & 7);
          gload16(Kg + (size_t)row * 64 + kg * 8,
                  smem + 8192 + (cur ^ 1) * 8192 + i * 4096 + wbase);
          gload16(Vg + (size_t)row * SS + kg * 8,
                  smem + 24576 + (cur ^ 1) * 8192 + i * 4096 + wbase);
        }
      }
      const char* Ks = smem + 8192 + cur * 8192;
      const char* Vs = smem + 24576 + cur * 8192;

      f32x4 accS[4];
      __builtin_amdgcn_s_setprio(1);
#pragma unroll
      for (int nf = 0; nf < 4; ++nf) {
        int row = nf * 16 + qrow_l;
        int rs = (row & 7) << 4;
        bf16x8 bk0 = *(const bf16x8*)(Ks + row * 128 + ((kgrp * 16) ^ rs));
        accS[nf] = __builtin_amdgcn_mfma_f32_16x16x32_bf16(bk0, aq[0], kz, 0, 0, 0);
        bf16x8 bk1 = *(const bf16x8*)(Ks + row * 128 + (((4 + kgrp) * 16) ^ rs));
        accS[nf] = __builtin_amdgcn_mfma_f32_16x16x32_bf16(bk1, aq[1], accS[nf], 0, 0, 0);
      }
      __builtin_amdgcn_s_setprio(0);

      const bool diag = (kvt == qt);
      float pmax = -1e30f;
#pragma unroll
      for (int nf = 0; nf < 4; ++nf)
#pragma unroll
        for (int r = 0; r < 4; ++r) {
          float s = accS[nf][r];
          if (diag && (kvt * 64 + nf * 16 + kgrp * 4 + r) > q_glob) s = -1e30f;
          accS[nf][r] = s;
          pmax = fmaxf(pmax, s);
        }

      if (__any(pmax > mI + THR)) {
        float t = pmax;
        t = fmaxf(t, __shfl_xor(t, 16));
        t = fmaxf(t, __shfl_xor(t, 32));
        float mn = fmaxf(mI, t);
        float al = exp2f(mI - mn);
        mI = mn;
#pragma unroll
        for (int r = 0; r < 4; ++r) {
          float alq = __shfl(al, (kgrp << 2) + r);
          accL[r] *= alq;
#pragma unroll
          for (int nf = 0; nf < 4; ++nf) accO[nf][r] *= alq;
        }
      }

#pragma unroll
      for (int nf = 0; nf < 4; ++nf) {
        float p0 = exp2f(accS[nf][0] - mI);
        float p1 = exp2f(accS[nf][1] - mI);
        float p2 = exp2f(accS[nf][2] - mI);
        float p3 = exp2f(accS[nf][3] - mI);
        uint2 pk;
        pk.x = (unsigned)bf16b(p0) | ((unsigned)bf16b(p1) << 16);
        pk.y = (unsigned)bf16b(p2) | ((unsigned)bf16b(p3) << 16);
        *(uint2*)(Ps + qrow_l * 128 + ((nf * 32 + kgrp * 8) ^ swz)) = pk;
      }

#pragma unroll
      for (int kk = 0; kk < 2; ++kk) {
        int pcol = (kk * 4 + kgrp) * 16;
        bf16x8 pa = *(const bf16x8*)(Ps + qrow_l * 128 + (pcol ^ swz));
        __builtin_amdgcn_s_setprio(1);
#pragma unroll
        for (int nf = 0; nf < 4; ++nf) {
          int vrow = nf * 16 + qrow_l;
          bf16x8 bv = *(const bf16x8*)(Vs + vrow * 128 + (pcol ^ ((vrow & 7) << 4)));
          accO[nf] = __builtin_amdgcn_mfma_f32_16x16x32_bf16(pa, bv, accO[nf], 0, 0, 0);
        }
        accL = __builtin_amdgcn_mfma_f32_16x16x32_bf16(pa, onev, accL, 0, 0, 0);
        __builtin_amdgcn_s_setprio(0);
      }

      __syncthreads();
      cur ^= 1;
    }

    if (pass == 0) {
#pragma unroll
      for (int i = 0; i < 2; ++i) {
        int row = i * 32 + srow;
        int kg = sslot ^ (row & 7);
        gload16(Qg + (size_t)(bx * 64 + row) * 64 + kg * 8, smem + i * 4096 + wbase);
      }
    }

    float inv[4];
#pragma unroll
    for (int r = 0; r < 4; ++r) inv[r] = 1.0f / accL[r];
#pragma unroll
    for (int nf = 0; nf < 4; ++nf) {
      int dh = nf * 16 + qrow_l;
#pragma unroll
      for (int r = 0; r < 4; ++r) {
        int qrow = qt * 64 + w * 16 + (kgrp << 2) + r;
        float o = accO[nf][r] * inv[r];
        ob[((size_t)b * SS + qrow) * DD + h * 64 + dh] = bf16b(o);
      }
    }

    if (pass == 0) {
      qt = bx;
      __syncthreads();
    }
  }
}

extern "C" void kernel_launch(void* const* d_in, const int* in_sizes, int n_in,
                              void* d_out, int out_size, void* d_ws, size_t ws_size,
                              hipStream_t stream) {
  const float* x = (const float*)d_in[0];
  const float* wqkv = (const float*)d_in[1];
  const float* wout = (const float*)d_in[2];
  float* out = (float*)d_out;
  char* ws = (char*)d_ws;
  unsigned short* xb  = (unsigned short*)(ws);              // [8192][768] bf16
  unsigned short* wqb = (unsigned short*)(ws + 12582912);   // [2304][768]
  unsigned short* wob = (unsigned short*)(ws + 16121856);   // [768][768]
  unsigned short* qb  = (unsigned short*)(ws + 17301504);   // [B][H][S][64]
  unsigned short* kb  = (unsigned short*)(ws + 29884416);   // [B][H][S][64]
  unsigned short* vtb = (unsigned short*)(ws + 42467328);   // [B][H][64][S]
  unsigned short* ob  = (unsigned short*)(ws + 55050240);   // [8192][768]
  // RoPE trig table aliases the ob region (gemm1 reads it BEFORE attn writes ob)
  float2* ttab = (float2*)(ws + 55050240);                  // [2048][32] float2 = 512KB

  k_convert<<<8704, 256, 0, stream>>>(x, wqkv, wout, xb, wqb, wob, ttab);

  dim3 g1(64, 18);  // M/128 x (3D)/128
  k_gemm<0><<<g1, 256, 0, stream>>>(xb, wqb, nullptr, qb, kb, vtb, ttab, 768, 2304);

  dim3 ga(16, 12, 4);  // paired q-tiles x H x B  (uniform 33 iters/block)
  k_attn<<<ga, 256, 0, stream>>>(qb, kb, vtb, ob);

  dim3 g2(64, 6);  // M/128 x D/128
  k_gemm<1><<<g2, 256, 0, stream>>>(ob, wob, out, nullptr, nullptr, nullptr, nullptr, 768, 768);
}

// Round 9
// 138.484 us; speedup vs baseline: 1.8294x; 1.0192x over previous
//
#include <hip/hip_runtime.h>
#include <hip/hip_bf16.h>

#define BB 4
#define SS 2048
#define DD 768
#define HH 12
#define TD 2304  // 3*D

typedef __bf16 bf16_t;
typedef bf16_t bf16x8 __attribute__((ext_vector_type(8)));
typedef float f32x4 __attribute__((ext_vector_type(4)));
typedef unsigned short u16x4 __attribute__((ext_vector_type(4)));

// async global->LDS, 16B per lane; LDS dest is wave-uniform base (+lane*16 by HW)
__device__ __forceinline__ void gload16(const void* g, void* l) {
  __builtin_amdgcn_global_load_lds((const __attribute__((address_space(1))) void*)g,
                                   (__attribute__((address_space(3))) void*)l, 16, 0, 0);
}

__device__ __forceinline__ unsigned short bf16b(float f) {
  return __builtin_bit_cast(unsigned short, (bf16_t)f);
}
__device__ __forceinline__ float bf16f(unsigned short u) {
  return (float)__builtin_bit_cast(bf16_t, u);
}

// ---------------- f32 -> bf16 convert (x, w_qkv, w_out) + RoPE trig table ----------------
__global__ __launch_bounds__(256) void k_convert(const float* __restrict__ x,
                                                 const float* __restrict__ wqkv,
                                                 const float* __restrict__ wout,
                                                 unsigned short* __restrict__ xb,
                                                 unsigned short* __restrict__ wqb,
                                                 unsigned short* __restrict__ wob,
                                                 float2* __restrict__ ttab) {
  const int n1 = BB * SS * DD / 4;     // 1572864 float4s
  const int n2 = n1 + TD * DD / 4;     // +442368
  const int n3 = n2 + DD * DD / 4;     // +147456 -> 2162688 = 8448*256
  int i = blockIdx.x * 256 + threadIdx.x;
  if (blockIdx.x >= 8448) {
    int idx = i - 8448 * 256;          // 0..65535 : s = idx>>5, i2 = idx&31
    if (idx < SS * 32) {
      int s = idx >> 5, i2 = idx & 31;
      float inv = __expf(-(float)i2 * (9.210340371976184f / 32.0f));
      float ang = (float)s * inv;
      float sn, cs;
      __sincosf(ang, &sn, &cs);
      ttab[idx] = make_float2(cs, sn);
    }
    return;
  }
  if (i >= n3) return;
  const float4* s;
  unsigned short* d;
  int j;
  if (i < n1)      { s = (const float4*)x;    d = xb;  j = i; }
  else if (i < n2) { s = (const float4*)wqkv; d = wqb; j = i - n1; }
  else             { s = (const float4*)wout; d = wob; j = i - n2; }
  float4 v = s[j];
  u16x4 o;
  o[0] = bf16b(v.x); o[1] = bf16b(v.y); o[2] = bf16b(v.z); o[3] = bf16b(v.w);
  *(u16x4*)(d + (size_t)j * 4) = o;
}

// ---------------- 128x128 bf16 GEMM, C = A * Bw^T, BK=32 double-buffered ----------------
// One barrier per K-step; prefetch next tile before compute so the vmcnt(0)
// drain at the barrier lands AFTER the MFMAs (attn-proven pattern).
// EPI==0: QKV epilogue (RoPE from ttab, LDS-staged coalesced stores; v transposed)
// EPI==1: plain f32 store to Cf [M][N]
template <int EPI>
__global__ __launch_bounds__(256) void k_gemm(const unsigned short* __restrict__ A,
                                              const unsigned short* __restrict__ Bw,
                                              float* __restrict__ Cf,
                                              unsigned short* __restrict__ qb,
                                              unsigned short* __restrict__ kb,
                                              unsigned short* __restrict__ vtb,
                                              const float2* __restrict__ ttab,
                                              int K, int N) {
  __shared__ char smem[32768];
  // buffer c at c*16384: A [128 rows][64B] at +0, B [128][64B] at +8192.
  // slot swizzle: byte ^= ((row>>2)&3)<<4, applied via pre-swizzled global source.
  const int tid = threadIdx.x;
  const int lane = tid & 63;
  const int w = tid >> 6, wm = w >> 1, wn = w & 1;
  const int m0 = blockIdx.x * 128, n0 = blockIdx.y * 128;

  const f32x4 zero4 = {0.f, 0.f, 0.f, 0.f};
  f32x4 acc[4][4];
#pragma unroll
  for (int a = 0; a < 4; ++a)
#pragma unroll
    for (int c = 0; c < 4; ++c) acc[a][c] = zero4;

  const int srow4 = tid >> 2;        // 0..63 (row within 64-row chunk)
  const int slot4 = tid & 3;         // 16B slot within 64B row
  const int wb4 = (tid & 192) * 16;  // wave-uniform LDS byte base (w*1024)

  // prologue: stage k-tile 0 into buffer 0
#pragma unroll
  for (int i = 0; i < 2; ++i) {
    int row = i * 64 + srow4;
    int kg = slot4 ^ ((row >> 2) & 3);
    gload16(A + (size_t)(m0 + row) * K + kg * 8, smem + i * 4096 + wb4);
    gload16(Bw + (size_t)(n0 + row) * K + kg * 8, smem + 8192 + i * 4096 + wb4);
  }
  __syncthreads();

  const int nk = K >> 5;  // 24 for K=768
  int cur = 0;
  for (int kt = 0; kt < nk; ++kt) {
    if (kt + 1 < nk) {
      int k0 = (kt + 1) << 5;
#pragma unroll
      for (int i = 0; i < 2; ++i) {
        int row = i * 64 + srow4;
        int kg = slot4 ^ ((row >> 2) & 3);
        gload16(A + (size_t)(m0 + row) * K + k0 + kg * 8,
                smem + (cur ^ 1) * 16384 + i * 4096 + wb4);
        gload16(Bw + (size_t)(n0 + row) * K + k0 + kg * 8,
                smem + (cur ^ 1) * 16384 + 8192 + i * 4096 + wb4);
      }
    }
    const char* As = smem + cur * 16384;
    const char* Bs = As + 8192;
    const int g16 = (lane >> 4) * 16;
    bf16x8 af[4], bfr[4];
#pragma unroll
    for (int mi = 0; mi < 4; ++mi) {
      int row = wm * 64 + mi * 16 + (lane & 15);
      af[mi] = *(const bf16x8*)(As + row * 64 + (g16 ^ (((row >> 2) & 3) << 4)));
    }
#pragma unroll
    for (int ni = 0; ni < 4; ++ni) {
      int row = wn * 64 + ni * 16 + (lane & 15);
      bfr[ni] = *(const bf16x8*)(Bs + row * 64 + (g16 ^ (((row >> 2) & 3) << 4)));
    }
    __builtin_amdgcn_s_setprio(1);
#pragma unroll
    for (int mi = 0; mi < 4; ++mi)
#pragma unroll
      for (int ni = 0; ni < 4; ++ni)
        acc[mi][ni] = __builtin_amdgcn_mfma_f32_16x16x32_bf16(af[mi], bfr[ni], acc[mi][ni], 0, 0, 0);
    __builtin_amdgcn_s_setprio(0);
    __syncthreads();  // vmcnt(0) drain lands AFTER compute -> prefetch hidden
    cur ^= 1;
  }
  // NOTE: all waves passed the final barrier -> smem reusable as C stage.

  if (EPI == 1) {
#pragma unroll
    for (int mi = 0; mi < 4; ++mi)
#pragma unroll
      for (int ni = 0; ni < 4; ++ni) {
        int ng = n0 + wn * 64 + ni * 16 + (lane & 15);
#pragma unroll
        for (int r = 0; r < 4; ++r) {
          int mg = m0 + wm * 64 + mi * 16 + ((lane >> 4) << 2) + r;
          Cf[(size_t)mg * N + ng] = acc[mi][ni][r];
        }
      }
  } else {
    const float SFT = 0.125f * 1.4426950408889634f;  // 1/sqrt(DH)*log2e folded into Q
    const int part = n0 / DD;          // 0=q 1=k 2=v (block-uniform: 128 | 768)
    const int h0 = (n0 % DD) >> 6;     // first of the 2 heads this block covers
    const int bB = m0 >> 11;           // batch (block-uniform: 128 | 2048)
    const int s0b = m0 & (SS - 1);     // base sequence position
    char* Cs = smem;                   // 32KB stage

    if (part < 2) {
      // ---- q/k: RoPE via table, row-major swizzled stage ----
#pragma unroll
      for (int mi = 0; mi < 4; ++mi) {
#pragma unroll
        for (int r = 0; r < 4; ++r) {
          int lr = wm * 64 + mi * 16 + ((lane >> 4) << 2) + r;
          const float2* tt = ttab + (size_t)(s0b + lr) * 32;
#pragma unroll
          for (int ni = 0; ni < 4; ++ni) {
            int lc = wn * 64 + ni * 16 + (lane & 15);
            int dh = lc & 63;
            float2 cs = tt[dh >> 1];
            float v = acc[mi][ni][r];
            float other = __shfl_xor(v, 1);
            float rr = (dh & 1) ? (other * cs.y + v * cs.x) : (v * cs.x - other * cs.y);
            if (part == 0) rr *= SFT;
            *(unsigned short*)(Cs + lr * 256 + ((lc * 2) ^ ((lr & 7) << 4))) = bf16b(rr);
          }
        }
      }
      __syncthreads();
      unsigned short* dp = (part == 0) ? qb : kb;
      const int j = tid & 15;
      const int head = j >> 3, dh0 = (j & 7) * 8;
#pragma unroll
      for (int t = 0; t < 8; ++t) {
        int lr = t * 16 + (tid >> 4);
        uint4 v16 = *(const uint4*)(Cs + lr * 256 + ((j * 16) ^ ((lr & 7) << 4)));
        *(uint4*)(dp + ((size_t)((bB * HH + h0 + head) * SS) + (s0b + lr)) * 64 + dh0) = v16;
      }
    } else {
      // ---- v: column-major swizzled stage -> transposed coalesced store ----
#pragma unroll
      for (int mi = 0; mi < 4; ++mi) {
#pragma unroll
        for (int r = 0; r < 4; ++r) {
          int lr = wm * 64 + mi * 16 + ((lane >> 4) << 2) + r;
#pragma unroll
          for (int ni = 0; ni < 4; ++ni) {
            int lc = wn * 64 + ni * 16 + (lane & 15);
            *(unsigned short*)(Cs + lc * 256 + ((lr * 2) ^ ((lc & 7) << 4))) =
                bf16b(acc[mi][ni][r]);
          }
        }
      }
      __syncthreads();
      const int j = tid & 15;
#pragma unroll
      for (int t = 0; t < 8; ++t) {
        int vrow = t * 16 + (tid >> 4);      // local col = head*64 + dh
        int head = vrow >> 6, dh = vrow & 63;
        uint4 v16 = *(const uint4*)(Cs + vrow * 256 + ((j * 16) ^ ((vrow & 7) << 4)));
        *(uint4*)(vtb + ((size_t)(bB * HH + h0 + head) * 64 + dh) * SS + s0b + j * 8) = v16;
      }
    }
  }
}

// ---------------- flash attention, causal, BQ=64, 4 waves, paired Q-tiles ----------------
__global__ __launch_bounds__(256, 4) void k_attn(const unsigned short* __restrict__ qb,
                                                 const unsigned short* __restrict__ kb,
                                                 const unsigned short* __restrict__ vtb,
                                                 unsigned short* __restrict__ ob) {
  __shared__ char smem[40960];
  const int tid = threadIdx.x, lane = tid & 63, w = tid >> 6;
  char* Ps = smem + w * 2048;

  const int bx = blockIdx.x;               // 0..15
  const int h = blockIdx.y, b = blockIdx.z;
  const size_t bh = (size_t)(b * HH + h);
  const unsigned short* Qg = qb + bh * SS * 64;
  const unsigned short* Kg = kb + bh * SS * 64;
  const unsigned short* Vg = vtb + bh * 64 * SS;

  const int srow = tid >> 3, sslot = tid & 7;
  const int wbase = w * 1024;
  const int qrow_l = lane & 15;
  const int kgrp = lane >> 4;
  const int swz = (qrow_l & 7) << 4;
  const f32x4 kz = {0.f, 0.f, 0.f, 0.f};
  const bf16_t oneb = (bf16_t)1.0f;
  const bf16x8 onev = {oneb, oneb, oneb, oneb, oneb, oneb, oneb, oneb};
  const float THR = 8.0f;

  int qt = 31 - bx;

#pragma unroll
  for (int i = 0; i < 2; ++i) {
    int row = i * 32 + srow;
    int kg = sslot ^ (row & 7);
    gload16(Qg + (size_t)(qt * 64 + row) * 64 + kg * 8, smem + i * 4096 + wbase);
    gload16(Kg + (size_t)row * 64 + kg * 8, smem + 8192 + i * 4096 + wbase);
    gload16(Vg + (size_t)row * SS + kg * 8, smem + 24576 + i * 4096 + wbase);
  }
  __syncthreads();

  int cur = 0;
  for (int pass = 0; pass < 2; ++pass) {
    bf16x8 aq[2];
    {
      int row = w * 16 + qrow_l;
#pragma unroll
      for (int kk = 0; kk < 2; ++kk) {
        int colb = (kk * 4 + kgrp) * 16;
        aq[kk] = *(const bf16x8*)(smem + row * 128 + (colb ^ ((row & 7) << 4)));
      }
    }

    float mI = -1e30f;
    f32x4 accO[4], accL = kz;
#pragma unroll
    for (int nf = 0; nf < 4; ++nf) accO[nf] = kz;
    const int nkv = qt + 1;
    const int q_glob = qt * 64 + w * 16 + qrow_l;

    for (int kvt = 0; kvt < nkv; ++kvt) {
      if (kvt + 1 < nkv) {
#pragma unroll
        for (int i = 0; i < 2; ++i) {
          int row = i * 32 + srow;
          int kg = sslot ^ (row & 7);
          gload16(Kg + (size_t)((kvt + 1) * 64 + row) * 64 + kg * 8,
                  smem + 8192 + (cur ^ 1) * 8192 + i * 4096 + wbase);
          gload16(Vg + (size_t)row * SS + (kvt + 1) * 64 + kg * 8,
                  smem + 24576 + (cur ^ 1) * 8192 + i * 4096 + wbase);
        }
      } else if (pass == 0) {
#pragma unroll
        for (int i = 0; i < 2; ++i) {
          int row = i * 32 + srow;
          int kg = sslot ^ (row & 7);
          gload16(Kg + (size_t)row * 64 + kg * 8,
                  smem + 8192 + (cur ^ 1) * 8192 + i * 4096 + wbase);
          gload16(Vg + (size_t)row * SS + kg * 8,
                  smem + 24576 + (cur ^ 1) * 8192 + i * 4096 + wbase);
        }
      }
      const char* Ks = smem + 8192 + cur * 8192;
      const char* Vs = smem + 24576 + cur * 8192;

      f32x4 accS[4];
      __builtin_amdgcn_s_setprio(1);
#pragma unroll
      for (int nf = 0; nf < 4; ++nf) {
        int row = nf * 16 + qrow_l;
        int rs = (row & 7) << 4;
        bf16x8 bk0 = *(const bf16x8*)(Ks + row * 128 + ((kgrp * 16) ^ rs));
        accS[nf] = __builtin_amdgcn_mfma_f32_16x16x32_bf16(bk0, aq[0], kz, 0, 0, 0);
        bf16x8 bk1 = *(const bf16x8*)(Ks + row * 128 + (((4 + kgrp) * 16) ^ rs));
        accS[nf] = __builtin_amdgcn_mfma_f32_16x16x32_bf16(bk1, aq[1], accS[nf], 0, 0, 0);
      }
      __builtin_amdgcn_s_setprio(0);

      const bool diag = (kvt == qt);
      float pmax = -1e30f;
#pragma unroll
      for (int nf = 0; nf < 4; ++nf)
#pragma unroll
        for (int r = 0; r < 4; ++r) {
          float s = accS[nf][r];
          if (diag && (kvt * 64 + nf * 16 + kgrp * 4 + r) > q_glob) s = -1e30f;
          accS[nf][r] = s;
          pmax = fmaxf(pmax, s);
        }

      if (__any(pmax > mI + THR)) {
        float t = pmax;
        t = fmaxf(t, __shfl_xor(t, 16));
        t = fmaxf(t, __shfl_xor(t, 32));
        float mn = fmaxf(mI, t);
        float al = exp2f(mI - mn);
        mI = mn;
#pragma unroll
        for (int r = 0; r < 4; ++r) {
          float alq = __shfl(al, (kgrp << 2) + r);
          accL[r] *= alq;
#pragma unroll
          for (int nf = 0; nf < 4; ++nf) accO[nf][r] *= alq;
        }
      }

#pragma unroll
      for (int nf = 0; nf < 4; ++nf) {
        float p0 = exp2f(accS[nf][0] - mI);
        float p1 = exp2f(accS[nf][1] - mI);
        float p2 = exp2f(accS[nf][2] - mI);
        float p3 = exp2f(accS[nf][3] - mI);
        uint2 pk;
        pk.x = (unsigned)bf16b(p0) | ((unsigned)bf16b(p1) << 16);
        pk.y = (unsigned)bf16b(p2) | ((unsigned)bf16b(p3) << 16);
        *(uint2*)(Ps + qrow_l * 128 + ((nf * 32 + kgrp * 8) ^ swz)) = pk;
      }

#pragma unroll
      for (int kk = 0; kk < 2; ++kk) {
        int pcol = (kk * 4 + kgrp) * 16;
        bf16x8 pa = *(const bf16x8*)(Ps + qrow_l * 128 + (pcol ^ swz));
        __builtin_amdgcn_s_setprio(1);
#pragma unroll
        for (int nf = 0; nf < 4; ++nf) {
          int vrow = nf * 16 + qrow_l;
          bf16x8 bv = *(const bf16x8*)(Vs + vrow * 128 + (pcol ^ ((vrow & 7) << 4)));
          accO[nf] = __builtin_amdgcn_mfma_f32_16x16x32_bf16(pa, bv, accO[nf], 0, 0, 0);
        }
        accL = __builtin_amdgcn_mfma_f32_16x16x32_bf16(pa, onev, accL, 0, 0, 0);
        __builtin_amdgcn_s_setprio(0);
      }

      __syncthreads();
      cur ^= 1;
    }

    if (pass == 0) {
#pragma unroll
      for (int i = 0; i < 2; ++i) {
        int row = i * 32 + srow;
        int kg = sslot ^ (row & 7);
        gload16(Qg + (size_t)(bx * 64 + row) * 64 + kg * 8, smem + i * 4096 + wbase);
      }
    }

    float inv[4];
#pragma unroll
    for (int r = 0; r < 4; ++r) inv[r] = 1.0f / accL[r];
#pragma unroll
    for (int nf = 0; nf < 4; ++nf) {
      int dh = nf * 16 + qrow_l;
#pragma unroll
      for (int r = 0; r < 4; ++r) {
        int qrow = qt * 64 + w * 16 + (kgrp << 2) + r;
        float o = accO[nf][r] * inv[r];
        ob[((size_t)b * SS + qrow) * DD + h * 64 + dh] = bf16b(o);
      }
    }

    if (pass == 0) {
      qt = bx;
      __syncthreads();
    }
  }
}

extern "C" void kernel_launch(void* const* d_in, const int* in_sizes, int n_in,
                              void* d_out, int out_size, void* d_ws, size_t ws_size,
                              hipStream_t stream) {
  const float* x = (const float*)d_in[0];
  const float* wqkv = (const float*)d_in[1];
  const float* wout = (const float*)d_in[2];
  float* out = (float*)d_out;
  char* ws = (char*)d_ws;
  unsigned short* xb  = (unsigned short*)(ws);              // [8192][768] bf16
  unsigned short* wqb = (unsigned short*)(ws + 12582912);   // [2304][768]
  unsigned short* wob = (unsigned short*)(ws + 16121856);   // [768][768]
  unsigned short* qb  = (unsigned short*)(ws + 17301504);   // [B][H][S][64]
  unsigned short* kb  = (unsigned short*)(ws + 29884416);   // [B][H][S][64]
  unsigned short* vtb = (unsigned short*)(ws + 42467328);   // [B][H][64][S]
  unsigned short* ob  = (unsigned short*)(ws + 55050240);   // [8192][768]
  // RoPE trig table aliases the ob region (gemm1 reads it BEFORE attn writes ob)
  float2* ttab = (float2*)(ws + 55050240);                  // [2048][32] float2 = 512KB

  k_convert<<<8704, 256, 0, stream>>>(x, wqkv, wout, xb, wqb, wob, ttab);

  dim3 g1(64, 18);  // M/128 x (3D)/128
  k_gemm<0><<<g1, 256, 0, stream>>>(xb, wqb, nullptr, qb, kb, vtb, ttab, 768, 2304);

  dim3 ga(16, 12, 4);  // paired q-tiles x H x B  (uniform 33 iters/block)
  k_attn<<<ga, 256, 0, stream>>>(qb, kb, vtb, ob);

  dim3 g2(64, 6);  // M/128 x D/128
  k_gemm<1><<<g2, 256, 0, stream>>>(ob, wob, out, nullptr, nullptr, nullptr, nullptr, 768, 768);
}

// Round 10
// 133.832 us; speedup vs baseline: 1.8930x; 1.0348x over previous
//
#include <hip/hip_runtime.h>
#include <hip/hip_bf16.h>

#define BB 4
#define SS 2048
#define DD 768
#define HH 12
#define TD 2304  // 3*D

typedef __bf16 bf16_t;
typedef bf16_t bf16x8 __attribute__((ext_vector_type(8)));
typedef float f32x4 __attribute__((ext_vector_type(4)));
typedef unsigned short u16x4 __attribute__((ext_vector_type(4)));

// async global->LDS, 16B per lane; LDS dest is wave-uniform base (+lane*16 by HW)
__device__ __forceinline__ void gload16(const void* g, void* l) {
  __builtin_amdgcn_global_load_lds((const __attribute__((address_space(1))) void*)g,
                                   (__attribute__((address_space(3))) void*)l, 16, 0, 0);
}

__device__ __forceinline__ unsigned short bf16b(float f) {
  return __builtin_bit_cast(unsigned short, (bf16_t)f);
}
__device__ __forceinline__ float bf16f(unsigned short u) {
  return (float)__builtin_bit_cast(bf16_t, u);
}

// ---------------- f32 -> bf16 convert (x, w_qkv, w_out) + RoPE trig table ----------------
__global__ __launch_bounds__(256) void k_convert(const float* __restrict__ x,
                                                 const float* __restrict__ wqkv,
                                                 const float* __restrict__ wout,
                                                 unsigned short* __restrict__ xb,
                                                 unsigned short* __restrict__ wqb,
                                                 unsigned short* __restrict__ wob,
                                                 float2* __restrict__ ttab) {
  const int n1 = BB * SS * DD / 4;     // 1572864 float4s
  const int n2 = n1 + TD * DD / 4;     // +442368
  const int n3 = n2 + DD * DD / 4;     // +147456 -> 2162688 = 8448*256
  int i = blockIdx.x * 256 + threadIdx.x;
  if (blockIdx.x >= 8448) {
    int idx = i - 8448 * 256;          // 0..65535 : s = idx>>5, i2 = idx&31
    if (idx < SS * 32) {
      int s = idx >> 5, i2 = idx & 31;
      float inv = __expf(-(float)i2 * (9.210340371976184f / 32.0f));
      float ang = (float)s * inv;
      float sn, cs;
      __sincosf(ang, &sn, &cs);
      ttab[idx] = make_float2(cs, sn);
    }
    return;
  }
  if (i >= n3) return;
  const float4* s;
  unsigned short* d;
  int j;
  if (i < n1)      { s = (const float4*)x;    d = xb;  j = i; }
  else if (i < n2) { s = (const float4*)wqkv; d = wqb; j = i - n1; }
  else             { s = (const float4*)wout; d = wob; j = i - n2; }
  float4 v = s[j];
  u16x4 o;
  o[0] = bf16b(v.x); o[1] = bf16b(v.y); o[2] = bf16b(v.z); o[3] = bf16b(v.w);
  *(u16x4*)(d + (size_t)j * 4) = o;
}

// ---------------- 128x128 bf16 GEMM, C = A * Bw^T ----------------
// BK=64 double-buffered with COUNTED vmcnt (T4): per iter, issue next-tile
// stage (8 gloads), then s_waitcnt vmcnt(8) -- waits only for the PREVIOUS
// tile's loads, leaving the new 8 in flight across the whole iteration --
// then raw s_barrier, ds_read+MFMA, raw s_barrier. Never drains vmcnt to 0
// in the main loop.
// EPI==0: QKV epilogue (RoPE from ttab, LDS-staged coalesced stores; v transposed)
// EPI==1: plain f32 store to Cf [M][N]
template <int EPI>
__global__ __launch_bounds__(256) void k_gemm(const unsigned short* __restrict__ A,
                                              const unsigned short* __restrict__ Bw,
                                              float* __restrict__ Cf,
                                              unsigned short* __restrict__ qb,
                                              unsigned short* __restrict__ kb,
                                              unsigned short* __restrict__ vtb,
                                              const float2* __restrict__ ttab,
                                              int K, int N) {
  __shared__ char smem[65536];
  // buffer c at c*32768: A [128 rows][128B] at +0, B at +16384.
  // slot swizzle byte ^= (row&7)<<4 via pre-swizzled global source (0-conflict, r0-r8).
  const int tid = threadIdx.x;
  const int lane = tid & 63;
  const int w = tid >> 6, wm = w >> 1, wn = w & 1;
  const int m0 = blockIdx.x * 128, n0 = blockIdx.y * 128;

  const f32x4 zero4 = {0.f, 0.f, 0.f, 0.f};
  f32x4 acc[4][4];
#pragma unroll
  for (int a = 0; a < 4; ++a)
#pragma unroll
    for (int c = 0; c < 4; ++c) acc[a][c] = zero4;

  const int srow = tid >> 3;         // 0..31 (row within 32-row chunk)
  const int sslot = tid & 7;         // 16B slot within 128B row
  const int wbase = (tid & 192) * 16;

  // prologue: stage k-tile 0 into buffer 0 (8 gloads/thread, no wait yet)
#pragma unroll
  for (int i = 0; i < 4; ++i) {
    int row = i * 32 + srow;
    int kg = sslot ^ (row & 7);
    gload16(A + (size_t)(m0 + row) * K + kg * 8, smem + i * 4096 + wbase);
    gload16(Bw + (size_t)(n0 + row) * K + kg * 8, smem + 16384 + i * 4096 + wbase);
  }

  const int nk = K >> 6;  // 12 for K=768
  int cur = 0;
  for (int kt = 0; kt < nk; ++kt) {
    if (kt + 1 < nk) {
      int k0 = (kt + 1) << 6;
#pragma unroll
      for (int i = 0; i < 4; ++i) {
        int row = i * 32 + srow;
        int kg = sslot ^ (row & 7);
        gload16(A + (size_t)(m0 + row) * K + k0 + kg * 8,
                smem + (cur ^ 1) * 32768 + i * 4096 + wbase);
        gload16(Bw + (size_t)(n0 + row) * K + k0 + kg * 8,
                smem + (cur ^ 1) * 32768 + 16384 + i * 4096 + wbase);
      }
      asm volatile("s_waitcnt vmcnt(8)" ::: "memory");  // prev tile arrived; 8 stay in flight
    } else {
      asm volatile("s_waitcnt vmcnt(0)" ::: "memory");  // last tile: drain
    }
    __builtin_amdgcn_s_barrier();   // all waves' prev-tile data visible

    const char* As = smem + cur * 32768;
    const char* Bs = As + 16384;
#pragma unroll
    for (int kk = 0; kk < 2; ++kk) {
      bf16x8 af[4], bfr[4];
      int colb = (kk * 4 + (lane >> 4)) * 16;
#pragma unroll
      for (int mi = 0; mi < 4; ++mi) {
        int row = wm * 64 + mi * 16 + (lane & 15);
        af[mi] = *(const bf16x8*)(As + row * 128 + (colb ^ ((row & 7) << 4)));
      }
#pragma unroll
      for (int ni = 0; ni < 4; ++ni) {
        int row = wn * 64 + ni * 16 + (lane & 15);
        bfr[ni] = *(const bf16x8*)(Bs + row * 128 + (colb ^ ((row & 7) << 4)));
      }
      __builtin_amdgcn_s_setprio(1);
#pragma unroll
      for (int mi = 0; mi < 4; ++mi)
#pragma unroll
        for (int ni = 0; ni < 4; ++ni)
          acc[mi][ni] = __builtin_amdgcn_mfma_f32_16x16x32_bf16(af[mi], bfr[ni], acc[mi][ni], 0, 0, 0);
      __builtin_amdgcn_s_setprio(0);
    }
    __builtin_amdgcn_s_barrier();   // all waves done reading buf[cur] before it's re-staged
    cur ^= 1;
  }
  // all waves past final barrier; epilogue C-stage uses smem[0,32768) (buf0),
  // disjoint from the last-read buffer (nk=12 even -> last reads were buf1).

  if (EPI == 1) {
#pragma unroll
    for (int mi = 0; mi < 4; ++mi)
#pragma unroll
      for (int ni = 0; ni < 4; ++ni) {
        int ng = n0 + wn * 64 + ni * 16 + (lane & 15);
#pragma unroll
        for (int r = 0; r < 4; ++r) {
          int mg = m0 + wm * 64 + mi * 16 + ((lane >> 4) << 2) + r;
          Cf[(size_t)mg * N + ng] = acc[mi][ni][r];
        }
      }
  } else {
    const float SFT = 0.125f * 1.4426950408889634f;  // 1/sqrt(DH)*log2e folded into Q
    const int part = n0 / DD;          // 0=q 1=k 2=v (block-uniform: 128 | 768)
    const int h0 = (n0 % DD) >> 6;     // first of the 2 heads this block covers
    const int bB = m0 >> 11;           // batch (block-uniform: 128 | 2048)
    const int s0b = m0 & (SS - 1);     // base sequence position
    char* Cs = smem;                   // 32KB stage (buf0)

    if (part < 2) {
      // ---- q/k: RoPE via table, row-major swizzled stage ----
#pragma unroll
      for (int mi = 0; mi < 4; ++mi) {
#pragma unroll
        for (int r = 0; r < 4; ++r) {
          int lr = wm * 64 + mi * 16 + ((lane >> 4) << 2) + r;
          const float2* tt = ttab + (size_t)(s0b + lr) * 32;
#pragma unroll
          for (int ni = 0; ni < 4; ++ni) {
            int lc = wn * 64 + ni * 16 + (lane & 15);
            int dh = lc & 63;
            float2 cs = tt[dh >> 1];
            float v = acc[mi][ni][r];
            float other = __shfl_xor(v, 1);
            float rr = (dh & 1) ? (other * cs.y + v * cs.x) : (v * cs.x - other * cs.y);
            if (part == 0) rr *= SFT;
            *(unsigned short*)(Cs + lr * 256 + ((lc * 2) ^ ((lr & 7) << 4))) = bf16b(rr);
          }
        }
      }
      __syncthreads();
      unsigned short* dp = (part == 0) ? qb : kb;
      const int j = tid & 15;
      const int head = j >> 3, dh0 = (j & 7) * 8;
#pragma unroll
      for (int t = 0; t < 8; ++t) {
        int lr = t * 16 + (tid >> 4);
        uint4 v16 = *(const uint4*)(Cs + lr * 256 + ((j * 16) ^ ((lr & 7) << 4)));
        *(uint4*)(dp + ((size_t)((bB * HH + h0 + head) * SS) + (s0b + lr)) * 64 + dh0) = v16;
      }
    } else {
      // ---- v: column-major swizzled stage -> transposed coalesced store ----
#pragma unroll
      for (int mi = 0; mi < 4; ++mi) {
#pragma unroll
        for (int r = 0; r < 4; ++r) {
          int lr = wm * 64 + mi * 16 + ((lane >> 4) << 2) + r;
#pragma unroll
          for (int ni = 0; ni < 4; ++ni) {
            int lc = wn * 64 + ni * 16 + (lane & 15);
            *(unsigned short*)(Cs + lc * 256 + ((lr * 2) ^ ((lc & 7) << 4))) =
                bf16b(acc[mi][ni][r]);
          }
        }
      }
      __syncthreads();
      const int j = tid & 15;
#pragma unroll
      for (int t = 0; t < 8; ++t) {
        int vrow = t * 16 + (tid >> 4);      // local col = head*64 + dh
        int head = vrow >> 6, dh = vrow & 63;
        uint4 v16 = *(const uint4*)(Cs + vrow * 256 + ((j * 16) ^ ((vrow & 7) << 4)));
        *(uint4*)(vtb + ((size_t)(bB * HH + h0 + head) * 64 + dh) * SS + s0b + j * 8) = v16;
      }
    }
  }
}

// ---------------- flash attention, causal, BQ=64, 4 waves, paired Q-tiles ----------------
__global__ __launch_bounds__(256, 4) void k_attn(const unsigned short* __restrict__ qb,
                                                 const unsigned short* __restrict__ kb,
                                                 const unsigned short* __restrict__ vtb,
                                                 unsigned short* __restrict__ ob) {
  __shared__ char smem[40960];
  const int tid = threadIdx.x, lane = tid & 63, w = tid >> 6;
  char* Ps = smem + w * 2048;

  const int bx = blockIdx.x;               // 0..15
  const int h = blockIdx.y, b = blockIdx.z;
  const size_t bh = (size_t)(b * HH + h);
  const unsigned short* Qg = qb + bh * SS * 64;
  const unsigned short* Kg = kb + bh * SS * 64;
  const unsigned short* Vg = vtb + bh * 64 * SS;

  const int srow = tid >> 3, sslot = tid & 7;
  const int wbase = w * 1024;
  const int qrow_l = lane & 15;
  const int kgrp = lane >> 4;
  const int swz = (qrow_l & 7) << 4;
  const f32x4 kz = {0.f, 0.f, 0.f, 0.f};
  const bf16_t oneb = (bf16_t)1.0f;
  const bf16x8 onev = {oneb, oneb, oneb, oneb, oneb, oneb, oneb, oneb};
  const float THR = 8.0f;

  int qt = 31 - bx;

#pragma unroll
  for (int i = 0; i < 2; ++i) {
    int row = i * 32 + srow;
    int kg = sslot ^ (row & 7);
    gload16(Qg + (size_t)(qt * 64 + row) * 64 + kg * 8, smem + i * 4096 + wbase);
    gload16(Kg + (size_t)row * 64 + kg * 8, smem + 8192 + i * 4096 + wbase);
    gload16(Vg + (size_t)row * SS + kg * 8, smem + 24576 + i * 4096 + wbase);
  }
  __syncthreads();

  int cur = 0;
  for (int pass = 0; pass < 2; ++pass) {
    bf16x8 aq[2];
    {
      int row = w * 16 + qrow_l;
#pragma unroll
      for (int kk = 0; kk < 2; ++kk) {
        int colb = (kk * 4 + kgrp) * 16;
        aq[kk] = *(const bf16x8*)(smem + row * 128 + (colb ^ ((row & 7) << 4)));
      }
    }

    float mI = -1e30f;
    f32x4 accO[4], accL = kz;
#pragma unroll
    for (int nf = 0; nf < 4; ++nf) accO[nf] = kz;
    const int nkv = qt + 1;
    const int q_glob = qt * 64 + w * 16 + qrow_l;

    for (int kvt = 0; kvt < nkv; ++kvt) {
      if (kvt + 1 < nkv) {
#pragma unroll
        for (int i = 0; i < 2; ++i) {
          int row = i * 32 + srow;
          int kg = sslot ^ (row & 7);
          gload16(Kg + (size_t)((kvt + 1) * 64 + row) * 64 + kg * 8,
                  smem + 8192 + (cur ^ 1) * 8192 + i * 4096 + wbase);
          gload16(Vg + (size_t)row * SS + (kvt + 1) * 64 + kg * 8,
                  smem + 24576 + (cur ^ 1) * 8192 + i * 4096 + wbase);
        }
      } else if (pass == 0) {
#pragma unroll
        for (int i = 0; i < 2; ++i) {
          int row = i * 32 + srow;
          int kg = sslot ^ (row & 7);
          gload16(Kg + (size_t)row * 64 + kg * 8,
                  smem + 8192 + (cur ^ 1) * 8192 + i * 4096 + wbase);
          gload16(Vg + (size_t)row * SS + kg * 8,
                  smem + 24576 + (cur ^ 1) * 8192 + i * 4096 + wbase);
        }
      }
      const char* Ks = smem + 8192 + cur * 8192;
      const char* Vs = smem + 24576 + cur * 8192;

      f32x4 accS[4];
      __builtin_amdgcn_s_setprio(1);
#pragma unroll
      for (int nf = 0; nf < 4; ++nf) {
        int row = nf * 16 + qrow_l;
        int rs = (row & 7) << 4;
        bf16x8 bk0 = *(const bf16x8*)(Ks + row * 128 + ((kgrp * 16) ^ rs));
        accS[nf] = __builtin_amdgcn_mfma_f32_16x16x32_bf16(bk0, aq[0], kz, 0, 0, 0);
        bf16x8 bk1 = *(const bf16x8*)(Ks + row * 128 + (((4 + kgrp) * 16) ^ rs));
        accS[nf] = __builtin_amdgcn_mfma_f32_16x16x32_bf16(bk1, aq[1], accS[nf], 0, 0, 0);
      }
      __builtin_amdgcn_s_setprio(0);

      const bool diag = (kvt == qt);
      float pmax = -1e30f;
#pragma unroll
      for (int nf = 0; nf < 4; ++nf)
#pragma unroll
        for (int r = 0; r < 4; ++r) {
          float s = accS[nf][r];
          if (diag && (kvt * 64 + nf * 16 + kgrp * 4 + r) > q_glob) s = -1e30f;
          accS[nf][r] = s;
          pmax = fmaxf(pmax, s);
        }

      if (__any(pmax > mI + THR)) {
        float t = pmax;
        t = fmaxf(t, __shfl_xor(t, 16));
        t = fmaxf(t, __shfl_xor(t, 32));
        float mn = fmaxf(mI, t);
        float al = exp2f(mI - mn);
        mI = mn;
#pragma unroll
        for (int r = 0; r < 4; ++r) {
          float alq = __shfl(al, (kgrp << 2) + r);
          accL[r] *= alq;
#pragma unroll
          for (int nf = 0; nf < 4; ++nf) accO[nf][r] *= alq;
        }
      }

#pragma unroll
      for (int nf = 0; nf < 4; ++nf) {
        float p0 = exp2f(accS[nf][0] - mI);
        float p1 = exp2f(accS[nf][1] - mI);
        float p2 = exp2f(accS[nf][2] - mI);
        float p3 = exp2f(accS[nf][3] - mI);
        uint2 pk;
        pk.x = (unsigned)bf16b(p0) | ((unsigned)bf16b(p1) << 16);
        pk.y = (unsigned)bf16b(p2) | ((unsigned)bf16b(p3) << 16);
        *(uint2*)(Ps + qrow_l * 128 + ((nf * 32 + kgrp * 8) ^ swz)) = pk;
      }

#pragma unroll
      for (int kk = 0; kk < 2; ++kk) {
        int pcol = (kk * 4 + kgrp) * 16;
        bf16x8 pa = *(const bf16x8*)(Ps + qrow_l * 128 + (pcol ^ swz));
        __builtin_amdgcn_s_setprio(1);
#pragma unroll
        for (int nf = 0; nf < 4; ++nf) {
          int vrow = nf * 16 + qrow_l;
          bf16x8 bv = *(const bf16x8*)(Vs + vrow * 128 + (pcol ^ ((vrow & 7) << 4)));
          accO[nf] = __builtin_amdgcn_mfma_f32_16x16x32_bf16(pa, bv, accO[nf], 0, 0, 0);
        }
        accL = __builtin_amdgcn_mfma_f32_16x16x32_bf16(pa, onev, accL, 0, 0, 0);
        __builtin_amdgcn_s_setprio(0);
      }

      __syncthreads();
      cur ^= 1;
    }

    if (pass == 0) {
#pragma unroll
      for (int i = 0; i < 2; ++i) {
        int row = i * 32 + srow;
        int kg = sslot ^ (row & 7);
        gload16(Qg + (size_t)(bx * 64 + row) * 64 + kg * 8, smem + i * 4096 + wbase);
      }
    }

    float inv[4];
#pragma unroll
    for (int r = 0; r < 4; ++r) inv[r] = 1.0f / accL[r];
#pragma unroll
    for (int nf = 0; nf < 4; ++nf) {
      int dh = nf * 16 + qrow_l;
#pragma unroll
      for (int r = 0; r < 4; ++r) {
        int qrow = qt * 64 + w * 16 + (kgrp << 2) + r;
        float o = accO[nf][r] * inv[r];
        ob[((size_t)b * SS + qrow) * DD + h * 64 + dh] = bf16b(o);
      }
    }

    if (pass == 0) {
      qt = bx;
      __syncthreads();
    }
  }
}

extern "C" void kernel_launch(void* const* d_in, const int* in_sizes, int n_in,
                              void* d_out, int out_size, void* d_ws, size_t ws_size,
                              hipStream_t stream) {
  const float* x = (const float*)d_in[0];
  const float* wqkv = (const float*)d_in[1];
  const float* wout = (const float*)d_in[2];
  float* out = (float*)d_out;
  char* ws = (char*)d_ws;
  unsigned short* xb  = (unsigned short*)(ws);              // [8192][768] bf16
  unsigned short* wqb = (unsigned short*)(ws + 12582912);   // [2304][768]
  unsigned short* wob = (unsigned short*)(ws + 16121856);   // [768][768]
  unsigned short* qb  = (unsigned short*)(ws + 17301504);   // [B][H][S][64]
  unsigned short* kb  = (unsigned short*)(ws + 29884416);   // [B][H][S][64]
  unsigned short* vtb = (unsigned short*)(ws + 42467328);   // [B][H][64][S]
  unsigned short* ob  = (unsigned short*)(ws + 55050240);   // [8192][768]
  // RoPE trig table aliases the ob region (gemm1 reads it BEFORE attn writes ob)
  float2* ttab = (float2*)(ws + 55050240);                  // [2048][32] float2 = 512KB

  k_convert<<<8704, 256, 0, stream>>>(x, wqkv, wout, xb, wqb, wob, ttab);

  dim3 g1(64, 18);  // M/128 x (3D)/128
  k_gemm<0><<<g1, 256, 0, stream>>>(xb, wqb, nullptr, qb, kb, vtb, ttab, 768, 2304);

  dim3 ga(16, 12, 4);  // paired q-tiles x H x B  (uniform 33 iters/block)
  k_attn<<<ga, 256, 0, stream>>>(qb, kb, vtb, ob);

  dim3 g2(64, 6);  // M/128 x D/128
  k_gemm<1><<<g2, 256, 0, stream>>>(ob, wob, out, nullptr, nullptr, nullptr, nullptr, 768, 768);
}